// Round 9
// baseline (462.287 us; speedup 1.0000x reference)
//
#include <hip/hip_runtime.h>
#include <hip/hip_bf16.h>

#define NN 200   // nodes
#define BB 256   // batch == attention sequence length
#define DD 128   // d_model == seq
#define DH 32    // head dim
#define NE 1600  // edges
#define LL 2     // layers

typedef short short8 __attribute__((ext_vector_type(8)));
typedef short short4a __attribute__((ext_vector_type(4)));
typedef float floatx4 __attribute__((ext_vector_type(4)));
using bf16 = __hip_bfloat16;

__device__ __forceinline__ short bfs(float x) {
  bf16 h = __float2bfloat16(x);
  return *(short*)&h;
}
__device__ __forceinline__ float b2f(short s) {
  union { unsigned u; float f; } cv;
  cv.u = ((unsigned)(unsigned short)s) << 16;
  return cv.f;
}

// XCD-clustered block decode (R4: FETCH 78->26MB). Requires NN%8==0.
__device__ __forceinline__ void swz_node(int bid, int per_node, int& node, int& rem) {
  int xcd = bid & 7;
  int slot = bid >> 3;
  int q = slot / per_node;
  node = xcd * (NN >> 3) + q;
  rem = slot - q * per_node;
}

// R9: WS row stride = 132 shorts (264B = 66 dwords). ds_read_b128 phase of 16
// lanes starts at bank 2r -> all distinct (stride 136/272B gave 4r%32: r,r+8
// collided -> 2x LDS cost, the 1.43M SQ_LDS_BANK_CONFLICT in R8's k_ffn).
#define WSTR 132

// issue 8 float4 loads of a [64][128] fp32 weight chunk into registers
__device__ __forceinline__ void ldw_regs(const float* __restrict__ wbase, int tid,
                                         float4* vr) {
#pragma unroll
  for (int i = 0; i < 8; i++) vr[i] = *(const float4*)(wbase + (i * 256 + tid) * 4);
}
// convert + write the chunk to WS (bf16, stride WSTR)
__device__ __forceinline__ void st_ws(const float4* vr, short* WS, int tid) {
#pragma unroll
  for (int i = 0; i < 8; i++) {
    int idx = i * 256 + tid;
    int rw = idx >> 5, k = (idx & 31) << 2;
    short4a p = {bfs(vr[i].x), bfs(vr[i].y), bfs(vr[i].z), bfs(vr[i].w)};
    *(short4a*)&WS[rw * WSTR + k] = p;
  }
}
__device__ __forceinline__ void stage_w(const float* __restrict__ wbase,
                                        short* WS, int tid) {
  float4 vr[8];
  ldw_regs(wbase, tid, vr);
  st_ws(vr, WS, tid);
}

// one 16-row x 64-col GEMM quarter against the staged chunk
__device__ __forceinline__ void gemm_q(const short8* af, const short* WS, int r,
                                       int quad, floatx4* acc) {
#pragma unroll
  for (int k0 = 0; k0 < 4; k0++) {
#pragma unroll
    for (int s = 0; s < 4; s++) {
      short8 bq = *(const short8*)&WS[(s * 16 + r) * WSTR + quad * 8 + k0 * 32];
      acc[s] = __builtin_amdgcn_mfma_f32_16x16x32_bf16(af[k0], bq, acc[s], 0, 0, 0);
    }
  }
}

// ---------------------------------------------------------------- QKV GEMM
// xdirect: A-operand read straight from fp32 x (transposed indexing) with
// on-the-fly bf16 convert — replaces the old k_transpose kernel for layer 0.
template <int MTPW>
__global__ __launch_bounds__(256) void k_gemm64(const bf16* __restrict__ A,
                                                const float* __restrict__ xsrc,
                                                int xdirect,
                                                const float* __restrict__ W,
                                                const float* __restrict__ bias,
                                                bf16* __restrict__ out, int nout,
                                                int astride, size_t woff, int wns,
                                                size_t boff, int bns, int relu,
                                                int nc_count) {
  __shared__ short WS[64 * WSTR];
  const int RSPLIT = 4 / MTPW;
  int per_node = nc_count * RSPLIT;
  int node, rem;
  swz_node(blockIdx.x, per_node, node, rem);
  int nc = rem / RSPLIT;
  int rh = rem - nc * RSPLIT;
  int tid = threadIdx.x;
  int w = tid >> 6, lane = tid & 63, r = lane & 15, quad = lane >> 4;
  int base_row = rh * 128 + w * (MTPW * 16);

  short8 areg[MTPW][4];
  if (xdirect) {
#pragma unroll
    for (int mt = 0; mt < MTPW; mt++) {
      const float* xrow =
          xsrc + ((size_t)(base_row + mt * 16 + r) * NN + node) * DD + quad * 8;
#pragma unroll
      for (int k = 0; k < 4; k++) {
        float4 a = *(const float4*)(xrow + k * 32);
        float4 b = *(const float4*)(xrow + k * 32 + 4);
        short8 v = {bfs(a.x), bfs(a.y), bfs(a.z), bfs(a.w),
                    bfs(b.x), bfs(b.y), bfs(b.z), bfs(b.w)};
        areg[mt][k] = v;
      }
    }
  } else {
#pragma unroll
    for (int mt = 0; mt < MTPW; mt++) {
      const bf16* arow =
          A + ((size_t)node * BB + base_row + mt * 16 + r) * (size_t)astride + quad * 8;
#pragma unroll
      for (int k = 0; k < 4; k++) areg[mt][k] = *(const short8*)(arow + k * 32);
    }
  }

  stage_w(W + woff + (size_t)node * (size_t)wns + (size_t)nc * 64 * DD, WS, tid);
  __syncthreads();

  floatx4 acc[MTPW][4];
  floatx4 z = {0.f, 0.f, 0.f, 0.f};
#pragma unroll
  for (int mt = 0; mt < MTPW; mt++)
#pragma unroll
    for (int s = 0; s < 4; s++) acc[mt][s] = z;

#pragma unroll
  for (int k0 = 0; k0 < 4; k0++) {
    short8 bq[4];
#pragma unroll
    for (int s = 0; s < 4; s++)
      bq[s] = *(const short8*)&WS[(s * 16 + r) * WSTR + quad * 8 + k0 * 32];
#pragma unroll
    for (int mt = 0; mt < MTPW; mt++)
#pragma unroll
      for (int s = 0; s < 4; s++)
        acc[mt][s] = __builtin_amdgcn_mfma_f32_16x16x32_bf16(areg[mt][k0], bq[s],
                                                             acc[mt][s], 0, 0, 0);
  }

  const float* bp = bias + boff + (size_t)node * (size_t)bns + nc * 64;
  float bv[4];
#pragma unroll
  for (int s = 0; s < 4; s++) bv[s] = bp[s * 16 + r];

  __syncthreads();  // all waves done reading WS; reuse as store bounce
  short* mybw = &WS[w * 2112];  // per-wave [16][68] within the wave's WS slice
  const size_t obase = (size_t)node * BB + base_row;
#pragma unroll
  for (int mt = 0; mt < MTPW; mt++) {
#pragma unroll
    for (int s = 0; s < 4; s++) {
#pragma unroll
      for (int i = 0; i < 4; i++) {
        float v = acc[mt][s][i] + bv[s];
        if (relu) v = v > 0.f ? v : 0.f;
        mybw[(quad * 4 + i) * 68 + s * 16 + r] = bfs(v);
      }
    }
#pragma unroll
    for (int j = 0; j < 2; j++) {
      int chunk = j * 64 + lane;
      int rowr = chunk >> 3, c8 = chunk & 7;
      short8 o = *(const short8*)&mybw[rowr * 68 + c8 * 8];
      *(short8*)((short*)out + (obase + mt * 16 + rowr) * (size_t)nout + nc * 64 + c8 * 8) = o;
    }
  }
}

// ---------------------------------------------------------------- fused FFN chain
// R8 rolling register-prefetch; R9 conflict-free stride + optional fp32-x
// residual (layer 0, replaces X read).
__global__ __launch_bounds__(256) void k_ffn(const bf16* __restrict__ QKV,
                                             const float* __restrict__ xf32,
                                             const float* __restrict__ Wo,
                                             const float* __restrict__ bo,
                                             bf16* __restrict__ X,
                                             const float* __restrict__ g1,
                                             const float* __restrict__ be1,
                                             const float* __restrict__ fW1,
                                             const float* __restrict__ fb1,
                                             const float* __restrict__ fW2,
                                             const float* __restrict__ fb2,
                                             const float* __restrict__ g2,
                                             const float* __restrict__ be2,
                                             size_t wso, int wns, size_t bso, int bns,
                                             int gstride,
                                             const float* __restrict__ W4,
                                             const float* __restrict__ C4,
                                             float* __restrict__ AS,
                                             float* __restrict__ ADv,
                                             float* __restrict__ HW0,
                                             float* __restrict__ HW1,
                                             int dofinal) {
  __shared__ short WS[64 * WSTR];  // weight chunk
  __shared__ short HB[64 * WSTR];  // h (bf16); per-wave slice doubles as fp32 bounce
  __shared__ short FB[64 * WSTR];  // f (bf16); per-wave slice doubles as fp32 bounce
  int node, bt;
  swz_node(blockIdx.x, 4, node, bt);
  int tid = threadIdx.x;
  int w = tid >> 6, lane = tid & 63, r = lane & 15, quad = lane >> 4;
  int rrow = lane >> 2, cg = lane & 3;
  int row0 = bt * 64 + w * 16;  // this wave's first row within the node

  // prefetch attn-out A-frags + residual rows (overlap first staging)
  const short* qrow = (const short*)QKV + ((size_t)node * BB + row0 + r) * 384 + quad * 8;
  short8 af[4];
#pragma unroll
  for (int k0 = 0; k0 < 4; k0++) af[k0] = *(const short8*)(qrow + k0 * 32);
  size_t xoff = ((size_t)node * BB + row0 + rrow) * DD + cg * 32;
  short8 xres[4];
  if (xf32) {
    const float* xr32 = xf32 + ((size_t)(row0 + rrow) * NN + node) * DD + cg * 32;
#pragma unroll
    for (int c = 0; c < 4; c++) {
      float4 a = *(const float4*)(xr32 + c * 8);
      float4 b = *(const float4*)(xr32 + c * 8 + 4);
      short8 v = {bfs(a.x), bfs(a.y), bfs(a.z), bfs(a.w),
                  bfs(b.x), bfs(b.y), bfs(b.z), bfs(b.w)};
      xres[c] = v;
    }
  } else {
#pragma unroll
    for (int c = 0; c < 4; c++)
      xres[c] = *(const short8*)((const short*)X + xoff + c * 8);
  }

  const float* WoN = Wo + wso + (size_t)node * (size_t)wns;
  const float* W1N = fW1 + wso + (size_t)node * (size_t)wns;
  const float* W2N = fW2 + wso + (size_t)node * (size_t)wns;

  floatx4 z = {0.f, 0.f, 0.f, 0.f};
  floatx4 acc[8];
  float vv[32];
  float bv[8];
  float4 wreg[8];

  // ================= phase A: Wo GEMM + residual + LN1 -> h (HB)
  ldw_regs(WoN, tid, wreg);
  st_ws(wreg, WS, tid);
  __syncthreads();
  ldw_regs(WoN + 64 * DD, tid, wreg);  // A1 in flight under gemm A0
#pragma unroll
  for (int s = 0; s < 8; s++) acc[s] = z;
  gemm_q(af, WS, r, quad, &acc[0]);
  __syncthreads();  // WS(A0) reads done
  st_ws(wreg, WS, tid);
  __syncthreads();
  ldw_regs(W1N, tid, wreg);  // B0 in flight under gemm A1 + LN1
  gemm_q(af, WS, r, quad, &acc[4]);

  const float* bpo = bo + bso + (size_t)node * (size_t)bns;
#pragma unroll
  for (int cch = 0; cch < 2; cch++)
#pragma unroll
    for (int s = 0; s < 4; s++) bv[cch * 4 + s] = bpo[cch * 64 + s * 16 + r];

  {
    float* BNC = (float*)&HB[w * 2112];  // [16][66] per-wave fp32 bounce
#pragma unroll
    for (int s = 0; s < 4; s++)
#pragma unroll
      for (int i = 0; i < 4; i++)
        BNC[(quad * 4 + i) * 66 + s * 16 + r] = acc[s][i] + bv[s];
    if (cg < 2) {
#pragma unroll
      for (int j = 0; j < 8; j++) {
        float4 t4 = *(const float4*)&BNC[rrow * 66 + (cg & 1) * 32 + j * 4];
        vv[j * 4 + 0] = t4.x; vv[j * 4 + 1] = t4.y;
        vv[j * 4 + 2] = t4.z; vv[j * 4 + 3] = t4.w;
      }
    }
#pragma unroll
    for (int s = 0; s < 4; s++)
#pragma unroll
      for (int i = 0; i < 4; i++)
        BNC[(quad * 4 + i) * 66 + s * 16 + r] = acc[4 + s][i] + bv[4 + s];
    if (cg >= 2) {
#pragma unroll
      for (int j = 0; j < 8; j++) {
        float4 t4 = *(const float4*)&BNC[rrow * 66 + (cg & 1) * 32 + j * 4];
        vv[j * 4 + 0] = t4.x; vv[j * 4 + 1] = t4.y;
        vv[j * 4 + 2] = t4.z; vv[j * 4 + 3] = t4.w;
      }
    }
  }

  float sum = 0.f;
#pragma unroll
  for (int c = 0; c < 4; c++)
#pragma unroll
    for (int j = 0; j < 8; j++) {
      vv[c * 8 + j] += b2f(xres[c][j]);
      sum += vv[c * 8 + j];
    }
  sum += __shfl_xor(sum, 1);
  sum += __shfl_xor(sum, 2);
  float mean = sum * (1.0f / 128.0f);
  float vs = 0.f;
#pragma unroll
  for (int j = 0; j < 32; j++) {
    float d = vv[j] - mean;
    vs += d * d;
  }
  vs += __shfl_xor(vs, 1);
  vs += __shfl_xor(vs, 2);
  float inv = rsqrtf(vs * (1.0f / 128.0f) + 1e-5f);
  {
    const float* gp = g1 + bso + (size_t)node * gstride + cg * 32;
    const float* bep = be1 + bso + (size_t)node * gstride + cg * 32;
#pragma unroll
    for (int c = 0; c < 8; c++) {
      float4 g4 = *(const float4*)(gp + c * 4);
      float4 b4 = *(const float4*)(bep + c * 4);
      vv[c * 4 + 0] = (vv[c * 4 + 0] - mean) * inv * g4.x + b4.x;
      vv[c * 4 + 1] = (vv[c * 4 + 1] - mean) * inv * g4.y + b4.y;
      vv[c * 4 + 2] = (vv[c * 4 + 2] - mean) * inv * g4.z + b4.z;
      vv[c * 4 + 3] = (vv[c * 4 + 3] - mean) * inv * g4.w + b4.w;
    }
  }
  // h -> HB bf16 (overwrites this wave's bounce region; in-order per-wave LDS)
  {
    short* hrow = &HB[(w * 16 + rrow) * WSTR + cg * 32];
#pragma unroll
    for (int c = 0; c < 4; c++) {
      short8 hs;
#pragma unroll
      for (int j = 0; j < 8; j++) hs[j] = bfs(vv[c * 8 + j]);
      *(short8*)(hrow + c * 8) = hs;
    }
  }

  // ================= phase B: f = relu(h@fW1^T + fb1) -> FB
  __syncthreads();  // WS(A1) reads done everywhere; h visible
  st_ws(wreg, WS, tid);  // B0 (waits for its loads)
  __syncthreads();
  ldw_regs(W1N + 64 * DD, tid, wreg);  // B1 in flight under gemm B0
  short8 hf[4];
#pragma unroll
  for (int k0 = 0; k0 < 4; k0++)
    hf[k0] = *(const short8*)&HB[(w * 16 + r) * WSTR + quad * 8 + k0 * 32];
#pragma unroll
  for (int s = 0; s < 8; s++) acc[s] = z;
  gemm_q(hf, WS, r, quad, &acc[0]);
  __syncthreads();  // WS(B0) reads done
  st_ws(wreg, WS, tid);  // B1
  __syncthreads();
  ldw_regs(W2N, tid, wreg);  // C0 in flight under gemm B1
  gemm_q(hf, WS, r, quad, &acc[4]);
  {
    const float* bp1 = fb1 + bso + (size_t)node * (size_t)bns;
#pragma unroll
    for (int cch = 0; cch < 2; cch++)
#pragma unroll
      for (int s = 0; s < 4; s++) {
        float bb = bp1[cch * 64 + s * 16 + r];
#pragma unroll
        for (int i = 0; i < 4; i++) {
          float v2 = acc[cch * 4 + s][i] + bb;
          FB[(w * 16 + quad * 4 + i) * WSTR + cch * 64 + s * 16 + r] =
              bfs(v2 > 0.f ? v2 : 0.f);
        }
      }
  }

  // ================= phase C: LN2(h + f@fW2^T + fb2) -> X / projections
  __syncthreads();  // WS(B1) reads done; f visible
  st_ws(wreg, WS, tid);  // C0
  __syncthreads();
  ldw_regs(W2N + 64 * DD, tid, wreg);  // C1 in flight under gemm C0
  short8 ff[4];
#pragma unroll
  for (int k0 = 0; k0 < 4; k0++)
    ff[k0] = *(const short8*)&FB[(w * 16 + r) * WSTR + quad * 8 + k0 * 32];
#pragma unroll
  for (int s = 0; s < 8; s++) acc[s] = z;
  gemm_q(ff, WS, r, quad, &acc[0]);
  __syncthreads();  // WS(C0) reads done
  st_ws(wreg, WS, tid);  // C1
  __syncthreads();
  gemm_q(ff, WS, r, quad, &acc[4]);

  const float* bp2 = fb2 + bso + (size_t)node * (size_t)bns;
#pragma unroll
  for (int cch = 0; cch < 2; cch++)
#pragma unroll
    for (int s = 0; s < 4; s++) bv[cch * 4 + s] = bp2[cch * 64 + s * 16 + r];

  {
    float* BNC = (float*)&FB[w * 2112];  // FB dead after ff loads (wave-private)
#pragma unroll
    for (int s = 0; s < 4; s++)
#pragma unroll
      for (int i = 0; i < 4; i++)
        BNC[(quad * 4 + i) * 66 + s * 16 + r] = acc[s][i] + bv[s];
    if (cg < 2) {
#pragma unroll
      for (int j = 0; j < 8; j++) {
        float4 t4 = *(const float4*)&BNC[rrow * 66 + (cg & 1) * 32 + j * 4];
        vv[j * 4 + 0] = t4.x; vv[j * 4 + 1] = t4.y;
        vv[j * 4 + 2] = t4.z; vv[j * 4 + 3] = t4.w;
      }
    }
#pragma unroll
    for (int s = 0; s < 4; s++)
#pragma unroll
      for (int i = 0; i < 4; i++)
        BNC[(quad * 4 + i) * 66 + s * 16 + r] = acc[4 + s][i] + bv[4 + s];
    if (cg >= 2) {
#pragma unroll
      for (int j = 0; j < 8; j++) {
        float4 t4 = *(const float4*)&BNC[rrow * 66 + (cg & 1) * 32 + j * 4];
        vv[j * 4 + 0] = t4.x; vv[j * 4 + 1] = t4.y;
        vv[j * 4 + 2] = t4.z; vv[j * 4 + 3] = t4.w;
      }
    }
  }

  sum = 0.f;
#pragma unroll
  for (int c = 0; c < 4; c++) {
    short8 hs = *(const short8*)&HB[(w * 16 + rrow) * WSTR + cg * 32 + c * 8];
#pragma unroll
    for (int j = 0; j < 8; j++) {
      vv[c * 8 + j] += b2f(hs[j]);
      sum += vv[c * 8 + j];
    }
  }
  sum += __shfl_xor(sum, 1);
  sum += __shfl_xor(sum, 2);
  mean = sum * (1.0f / 128.0f);
  vs = 0.f;
#pragma unroll
  for (int j = 0; j < 32; j++) {
    float d = vv[j] - mean;
    vs += d * d;
  }
  vs += __shfl_xor(vs, 1);
  vs += __shfl_xor(vs, 2);
  inv = rsqrtf(vs * (1.0f / 128.0f) + 1e-5f);
  {
    const float* gp = g2 + bso + (size_t)node * gstride + cg * 32;
    const float* bep = be2 + bso + (size_t)node * gstride + cg * 32;
#pragma unroll
    for (int c = 0; c < 8; c++) {
      float4 g4 = *(const float4*)(gp + c * 4);
      float4 b4 = *(const float4*)(bep + c * 4);
      vv[c * 4 + 0] = (vv[c * 4 + 0] - mean) * inv * g4.x + b4.x;
      vv[c * 4 + 1] = (vv[c * 4 + 1] - mean) * inv * g4.y + b4.y;
      vv[c * 4 + 2] = (vv[c * 4 + 2] - mean) * inv * g4.z + b4.z;
      vv[c * 4 + 3] = (vv[c * 4 + 3] - mean) * inv * g4.w + b4.w;
    }
  }

  if (!dofinal) {
#pragma unroll
    for (int c = 0; c < 4; c++) {
      short8 os;
#pragma unroll
      for (int j = 0; j < 8; j++) os[j] = bfs(vv[c * 8 + j]);
      *(short8*)((short*)X + xoff + c * 8) = os;
    }
  } else {
    float a0 = 0.f, a1 = 0.f, a2 = 0.f, a3 = 0.f;
#pragma unroll
    for (int c = 0; c < 8; c++) {
      float4 w0 = *(const float4*)(W4 + cg * 32 + c * 4);
      float4 w1 = *(const float4*)(W4 + 128 + cg * 32 + c * 4);
      float4 w2 = *(const float4*)(W4 + 256 + cg * 32 + c * 4);
      float4 w3 = *(const float4*)(W4 + 384 + cg * 32 + c * 4);
      a0 += vv[c * 4] * w0.x + vv[c * 4 + 1] * w0.y + vv[c * 4 + 2] * w0.z + vv[c * 4 + 3] * w0.w;
      a1 += vv[c * 4] * w1.x + vv[c * 4 + 1] * w1.y + vv[c * 4 + 2] * w1.z + vv[c * 4 + 3] * w1.w;
      a2 += vv[c * 4] * w2.x + vv[c * 4 + 1] * w2.y + vv[c * 4 + 2] * w2.z + vv[c * 4 + 3] * w2.w;
      a3 += vv[c * 4] * w3.x + vv[c * 4 + 1] * w3.y + vv[c * 4 + 2] * w3.z + vv[c * 4 + 3] * w3.w;
    }
    a0 += __shfl_xor(a0, 1); a0 += __shfl_xor(a0, 2);
    a1 += __shfl_xor(a1, 1); a1 += __shfl_xor(a1, 2);
    a2 += __shfl_xor(a2, 1); a2 += __shfl_xor(a2, 2);
    a3 += __shfl_xor(a3, 1); a3 += __shfl_xor(a3, 2);
    if (cg == 0) {
      int grow = node * BB + row0 + rrow;
      AS[grow] = a0 + C4[0];
      ADv[grow] = a1 + C4[1];
      HW0[grow] = a2 + C4[2];
      HW1[grow] = a3 + C4[3];
    }
  }
}

// ---------------------------------------------------------------- MFMA attention
__global__ __launch_bounds__(256) void k_attn(bf16* __restrict__ QKV) {
  __shared__ short VT[32 * 264];
  __shared__ short Pw[4 * 2560];
  int node, h;
  swz_node(blockIdx.x, 4, node, h);
  int tid = threadIdx.x;
  int wave = tid >> 6, lane = tid & 63, quad = lane >> 4, l15 = lane & 15;
  short* sbase = (short*)(QKV + (size_t)node * BB * 384);

  int q0 = wave * 64;
  short8 qf[4];
#pragma unroll
  for (int qt = 0; qt < 4; qt++)
    qf[qt] = *(const short8*)(sbase + (size_t)(q0 + qt * 16 + l15) * 384 + h * 32 + quad * 8);

#pragma unroll
  for (int it = 0; it < 4; it++) {
    int i = it * 256 + tid;
    int key = i >> 2, dq = (i & 3) << 3;
    short8 v8 = *(const short8*)(sbase + (size_t)key * 384 + 256 + h * 32 + dq);
#pragma unroll
    for (int j = 0; j < 8; j++) VT[(dq + j) * 264 + key] = v8[j];
  }
  __syncthreads();

  floatx4 zz = {0.f, 0.f, 0.f, 0.f};
  floatx4 acc[2][4];
#pragma unroll
  for (int dt = 0; dt < 2; dt++)
#pragma unroll
    for (int qt = 0; qt < 4; qt++) acc[dt][qt] = zz;
  float lp[4] = {0.f, 0.f, 0.f, 0.f};
  const float scale = 0.17677669529663689f;
  short* mypw = &Pw[wave * 2560];

#define KADDR(kt) (const short8*)(sbase + (size_t)((kt) * 16 + l15) * 384 + 128 + h * 32 + quad * 8)
  short8 kfA = *KADDR(0);
  short8 kfB = *KADDR(1);

  for (int g = 0; g < 8; g++) {
    short8 vf0 = *(const short8*)(&VT[l15 * 264 + g * 32 + quad * 8]);
    short8 vf1 = *(const short8*)(&VT[(16 + l15) * 264 + g * 32 + quad * 8]);
    short8 nA = kfA, nB = kfB;
    if (g < 7) {
      nA = *KADDR(g * 2 + 2);
      nB = *KADDR(g * 2 + 3);
    }
#pragma unroll
    for (int sub = 0; sub < 2; sub++) {
      short8 kf = sub ? kfB : kfA;
#pragma unroll
      for (int qt = 0; qt < 4; qt++) {
        floatx4 st = __builtin_amdgcn_mfma_f32_16x16x32_bf16(kf, qf[qt], zz, 0, 0, 0);
        float e0 = __expf(st[0] * scale);
        float e1 = __expf(st[1] * scale);
        float e2 = __expf(st[2] * scale);
        float e3 = __expf(st[3] * scale);
        lp[qt] += (e0 + e1) + (e2 + e3);
        short4a p = {bfs(e0), bfs(e1), bfs(e2), bfs(e3)};
        *(short4a*)(mypw + qt * 640 + l15 * 40 + sub * 16 + quad * 4) = p;
      }
    }
#pragma unroll
    for (int qt = 0; qt < 4; qt++) {
      short8 pf = *(const short8*)(mypw + qt * 640 + l15 * 40 + quad * 8);
      acc[0][qt] = __builtin_amdgcn_mfma_f32_16x16x32_bf16(vf0, pf, acc[0][qt], 0, 0, 0);
      acc[1][qt] = __builtin_amdgcn_mfma_f32_16x16x32_bf16(vf1, pf, acc[1][qt], 0, 0, 0);
    }
    kfA = nA;
    kfB = nB;
  }
#undef KADDR

  float inv[4];
#pragma unroll
  for (int qt = 0; qt < 4; qt++) {
    float lq = lp[qt];
    lq += __shfl_xor(lq, 16);
    lq += __shfl_xor(lq, 32);
    inv[qt] = 1.0f / lq;
  }

#pragma unroll
  for (int qt = 0; qt < 4; qt++)
#pragma unroll
    for (int dt = 0; dt < 2; dt++)
#pragma unroll
      for (int i = 0; i < 4; i++)
        mypw[(qt * 16 + l15) * 40 + dt * 16 + quad * 4 + i] = bfs(acc[dt][qt][i] * inv[qt]);

#pragma unroll
  for (int r = 0; r < 4; r++) {
    int chunk = r * 64 + lane;
    int query = chunk >> 2, d8 = (chunk & 3) * 8;
    short8 o = *(const short8*)(mypw + query * 40 + d8);
    *(short8*)(sbase + (size_t)(q0 + query) * 384 + h * 32 + d8) = o;
  }
}

// ---------------------------------------------------------------- fold GAT/pred/fc
__global__ __launch_bounds__(256) void k_prep(const float* __restrict__ gatW,
                                              const float* __restrict__ attS,
                                              const float* __restrict__ attD,
                                              const float* __restrict__ predW,
                                              const float* __restrict__ fcW,
                                              const float* __restrict__ fcb,
                                              float* __restrict__ W4,
                                              float* __restrict__ C4) {
  __shared__ float U[4][64];
  int t = threadIdx.x;
  int tt = t >> 6, f = t & 63;
  float u = 0.f;
  if (tt == 0) {
    for (int g = 0; g < 64; g++) u += gatW[g * 64 + f] * attS[g];
  } else if (tt == 1) {
    for (int g = 0; g < 64; g++) u += gatW[g * 64 + f] * attD[g];
  } else if (tt == 2) {
    for (int g = 0; g < 64; g++) u += gatW[g * 64 + f] * predW[g];
  } else {
    for (int g = 0; g < 64; g++) u += gatW[g * 64 + f] * predW[64 + g];
  }
  U[tt][f] = u;
  __syncthreads();
  for (int idx = t; idx < 512; idx += 256) {
    int v = idx >> 7, d = idx & 127;
    float w = 0.f;
#pragma unroll
    for (int ff = 0; ff < 64; ff++) w += fcW[ff * 128 + d] * U[v][ff];
    W4[v * 128 + d] = w;
  }
  if (t < 4) {
    float c = 0.f;
#pragma unroll
    for (int ff = 0; ff < 64; ff++) c += fcb[ff] * U[t][ff];
    C4[t] = c;
  }
}

// ---------------------------------------------------------------- GAT: one block per batch
__global__ __launch_bounds__(256) void k_gat(const int* __restrict__ EI,
                                             const float* __restrict__ AS,
                                             const float* __restrict__ ADv,
                                             const float* __restrict__ HW0,
                                             const float* __restrict__ HW1,
                                             const float* __restrict__ gatB,
                                             const float* __restrict__ predW,
                                             const float* __restrict__ predB,
                                             float* __restrict__ OUT) {
  __shared__ float sAS[NN], sAD[NN], sH0[NN], sH1[NN];
  __shared__ float n0[NN], n1[NN], den[NN];
  __shared__ float cc[2];
  int b = blockIdx.x;
  int t = threadIdx.x;
  int base = b * NN;
  for (int i = t; i < NN; i += 256) {
    sAS[i] = AS[base + i];
    sAD[i] = ADv[base + i];
    sH0[i] = HW0[base + i];
    sH1[i] = HW1[base + i];
    n0[i] = 0.f;
    n1[i] = 0.f;
    den[i] = 0.f;
  }
  if (t < 64) {
    float p0 = gatB[t] * predW[t];
    float p1 = gatB[t] * predW[64 + t];
#pragma unroll
    for (int off = 32; off; off >>= 1) {
      p0 += __shfl_down(p0, off);
      p1 += __shfl_down(p1, off);
    }
    if (t == 0) {
      cc[0] = p0 + predB[0];
      cc[1] = p1 + predB[1];
    }
  }
  __syncthreads();

  for (int i = t; i < NE + NN; i += 256) {
    int s, d;
    if (i < NE) {
      s = EI[i];
      d = EI[NE + i];
    } else {
      s = d = i - NE;  // self loop
    }
    float ev = sAS[s] + sAD[d];
    float lr = ev > 0.f ? ev : 0.2f * ev;
    float w = __expf(lr);
    atomicAdd(&n0[d], w * sH0[s]);
    atomicAdd(&n1[d], w * sH1[s]);
    atomicAdd(&den[d], w);
  }
  __syncthreads();

  for (int i = t; i < NN; i += 256) {
    float inv = 1.0f / (den[i] + 1e-16f);
    OUT[2 * (base + i)] = n0[i] * inv + cc[0];
    OUT[2 * (base + i) + 1] = n1[i] * inv + cc[1];
  }
}

// ================================================================ launch
extern "C" void kernel_launch(void* const* d_in, const int* in_sizes, int n_in,
                              void* d_out, int out_size, void* d_ws, size_t ws_size,
                              hipStream_t stream) {
  const float* x = (const float*)d_in[0];
  const int* ei = (const int*)d_in[1];
  const float* Wqkv = (const float*)d_in[2];
  const float* bqkv = (const float*)d_in[3];
  const float* Wo = (const float*)d_in[4];
  const float* bo = (const float*)d_in[5];
  const float* g1 = (const float*)d_in[6];
  const float* be1 = (const float*)d_in[7];
  const float* fW1 = (const float*)d_in[8];
  const float* fb1 = (const float*)d_in[9];
  const float* fW2 = (const float*)d_in[10];
  const float* fb2 = (const float*)d_in[11];
  const float* g2 = (const float*)d_in[12];
  const float* be2 = (const float*)d_in[13];
  const float* fcW = (const float*)d_in[14];
  const float* fcb = (const float*)d_in[15];
  const float* gatW = (const float*)d_in[16];
  const float* attS = (const float*)d_in[17];
  const float* attD = (const float*)d_in[18];
  const float* gatB = (const float*)d_in[19];
  const float* predW = (const float*)d_in[20];
  const float* predB = (const float*)d_in[21];

  const size_t NEED = 53477376;
  if (ws_size < NEED) return;

  char* ws = (char*)d_ws;
  bf16* X = (bf16*)(ws);                  // [N][B][128]   0 .. 13,107,200
  bf16* QKV = (bf16*)(ws + 13107200);     // [N][B][384]  .. 52,428,800
  float* W4 = (float*)(ws + 52428800);    // [4][128]
  float* C4 = (float*)(ws + 52430848);    // [4]
  float* AS = (float*)(ws + 52431872);    // [51200]
  float* ADv = (float*)(ws + 52636672);   // [51200]
  float* HW0 = (float*)(ws + 52841472);   // [51200]
  float* HW1 = (float*)(ws + 53046272);   // [51200]

  k_prep<<<1, 256, 0, stream>>>(gatW, attS, attD, predW, fcW, fcb, W4, C4);

  for (int l = 0; l < LL; l++) {
    size_t w3o = (size_t)l * 384 * DD, b3o = (size_t)l * 384;
    size_t wso = (size_t)l * DD * DD, bso = (size_t)l * DD;
    k_gemm64<4><<<6 * NN, 256, 0, stream>>>(X, x, (l == 0) ? 1 : 0, Wqkv, bqkv,
                                            QKV, 384, DD, w3o, LL * 384 * DD,
                                            b3o, LL * 384, 0, 6);
    k_attn<<<NN * 4, 256, 0, stream>>>(QKV);
    k_ffn<<<4 * NN, 256, 0, stream>>>(QKV, (l == 0) ? x : nullptr, Wo, bo, X,
                                      g1, be1, fW1, fb1, fW2, fb2, g2, be2,
                                      wso, LL * DD * DD, bso, LL * DD, LL * DD,
                                      W4, C4, AS, ADv, HW0, HW1,
                                      (l == LL - 1) ? 1 : 0);
  }

  k_gat<<<BB, 256, 0, stream>>>(ei, AS, ADv, HW0, HW1, gatB, predW, predB,
                                (float*)d_out);
}

// Round 10
// 410.948 us; speedup vs baseline: 1.1249x; 1.1249x over previous
//
#include <hip/hip_runtime.h>
#include <hip/hip_bf16.h>

#define NN 200   // nodes
#define BB 256   // batch == attention sequence length
#define DD 128   // d_model == seq
#define DH 32    // head dim
#define NE 1600  // edges
#define LL 2     // layers

typedef short short8 __attribute__((ext_vector_type(8)));
typedef short short4a __attribute__((ext_vector_type(4)));
typedef float floatx4 __attribute__((ext_vector_type(4)));
using bf16 = __hip_bfloat16;

__device__ __forceinline__ short bfs(float x) {
  bf16 h = __float2bfloat16(x);
  return *(short*)&h;
}
__device__ __forceinline__ float b2f(short s) {
  union { unsigned u; float f; } cv;
  cv.u = ((unsigned)(unsigned short)s) << 16;
  return cv.f;
}

// XCD-clustered block decode (R4: FETCH 78->26MB). Requires NN%8==0.
__device__ __forceinline__ void swz_node(int bid, int per_node, int& node, int& rem) {
  int xcd = bid & 7;
  int slot = bid >> 3;
  int q = slot / per_node;
  node = xcd * (NN >> 3) + q;
  rem = slot - q * per_node;
}

// WS row stride = 136 shorts (272B). NOTE R9 ERRATum: 132 (264B) halved bank
// conflicts but broke 16B alignment of row bases -> every ds_read_b128 split
// into b64 pairs, +48% k_ffn time. Row base MUST stay 16B-aligned; the 1.4M
// conflict counter lives on the bounce/write paths, not the GEMM-read path.

// issue 8 float4 loads of a [64][128] fp32 weight chunk into registers
__device__ __forceinline__ void ldw_regs(const float* __restrict__ wbase, int tid,
                                         float4* vr) {
#pragma unroll
  for (int i = 0; i < 8; i++) vr[i] = *(const float4*)(wbase + (i * 256 + tid) * 4);
}
// convert + write the chunk to WS (bf16, stride 136)
__device__ __forceinline__ void st_ws(const float4* vr, short* WS, int tid) {
#pragma unroll
  for (int i = 0; i < 8; i++) {
    int idx = i * 256 + tid;
    int rw = idx >> 5, k = (idx & 31) << 2;
    short4a p = {bfs(vr[i].x), bfs(vr[i].y), bfs(vr[i].z), bfs(vr[i].w)};
    *(short4a*)&WS[rw * 136 + k] = p;
  }
}
__device__ __forceinline__ void stage_w(const float* __restrict__ wbase,
                                        short* WS, int tid) {
  float4 vr[8];
  ldw_regs(wbase, tid, vr);
  st_ws(vr, WS, tid);
}

// one 16-row x 64-col GEMM quarter against the staged chunk
__device__ __forceinline__ void gemm_q(const short8* af, const short* WS, int r,
                                       int quad, floatx4* acc) {
#pragma unroll
  for (int k0 = 0; k0 < 4; k0++) {
#pragma unroll
    for (int s = 0; s < 4; s++) {
      short8 bq = *(const short8*)&WS[(s * 16 + r) * 136 + quad * 8 + k0 * 32];
      acc[s] = __builtin_amdgcn_mfma_f32_16x16x32_bf16(af[k0], bq, acc[s], 0, 0, 0);
    }
  }
}

// ---------------------------------------------------------------- QKV GEMM
// xdirect: A-operand read straight from fp32 x (transposed indexing) with
// on-the-fly bf16 convert — replaces the old k_transpose kernel for layer 0.
template <int MTPW>
__global__ __launch_bounds__(256) void k_gemm64(const bf16* __restrict__ A,
                                                const float* __restrict__ xsrc,
                                                int xdirect,
                                                const float* __restrict__ W,
                                                const float* __restrict__ bias,
                                                bf16* __restrict__ out, int nout,
                                                int astride, size_t woff, int wns,
                                                size_t boff, int bns, int relu,
                                                int nc_count) {
  __shared__ short WS[64 * 136];  // 17 KB
  const int RSPLIT = 4 / MTPW;
  int per_node = nc_count * RSPLIT;
  int node, rem;
  swz_node(blockIdx.x, per_node, node, rem);
  int nc = rem / RSPLIT;
  int rh = rem - nc * RSPLIT;
  int tid = threadIdx.x;
  int w = tid >> 6, lane = tid & 63, r = lane & 15, quad = lane >> 4;
  int base_row = rh * 128 + w * (MTPW * 16);

  short8 areg[MTPW][4];
  if (xdirect) {
#pragma unroll
    for (int mt = 0; mt < MTPW; mt++) {
      const float* xrow =
          xsrc + ((size_t)(base_row + mt * 16 + r) * NN + node) * DD + quad * 8;
#pragma unroll
      for (int k = 0; k < 4; k++) {
        float4 a = *(const float4*)(xrow + k * 32);
        float4 b = *(const float4*)(xrow + k * 32 + 4);
        short8 v = {bfs(a.x), bfs(a.y), bfs(a.z), bfs(a.w),
                    bfs(b.x), bfs(b.y), bfs(b.z), bfs(b.w)};
        areg[mt][k] = v;
      }
    }
  } else {
#pragma unroll
    for (int mt = 0; mt < MTPW; mt++) {
      const bf16* arow =
          A + ((size_t)node * BB + base_row + mt * 16 + r) * (size_t)astride + quad * 8;
#pragma unroll
      for (int k = 0; k < 4; k++) areg[mt][k] = *(const short8*)(arow + k * 32);
    }
  }

  stage_w(W + woff + (size_t)node * (size_t)wns + (size_t)nc * 64 * DD, WS, tid);
  __syncthreads();

  floatx4 acc[MTPW][4];
  floatx4 z = {0.f, 0.f, 0.f, 0.f};
#pragma unroll
  for (int mt = 0; mt < MTPW; mt++)
#pragma unroll
    for (int s = 0; s < 4; s++) acc[mt][s] = z;

#pragma unroll
  for (int k0 = 0; k0 < 4; k0++) {
    short8 bq[4];
#pragma unroll
    for (int s = 0; s < 4; s++)
      bq[s] = *(const short8*)&WS[(s * 16 + r) * 136 + quad * 8 + k0 * 32];
#pragma unroll
    for (int mt = 0; mt < MTPW; mt++)
#pragma unroll
      for (int s = 0; s < 4; s++)
        acc[mt][s] = __builtin_amdgcn_mfma_f32_16x16x32_bf16(areg[mt][k0], bq[s],
                                                             acc[mt][s], 0, 0, 0);
  }

  const float* bp = bias + boff + (size_t)node * (size_t)bns + nc * 64;
  float bv[4];
#pragma unroll
  for (int s = 0; s < 4; s++) bv[s] = bp[s * 16 + r];

  __syncthreads();  // all waves done reading WS; reuse as store bounce
  short* mybw = &WS[w * 1088];  // per-wave [16][68]
  const size_t obase = (size_t)node * BB + base_row;
#pragma unroll
  for (int mt = 0; mt < MTPW; mt++) {
#pragma unroll
    for (int s = 0; s < 4; s++) {
#pragma unroll
      for (int i = 0; i < 4; i++) {
        float v = acc[mt][s][i] + bv[s];
        if (relu) v = v > 0.f ? v : 0.f;
        mybw[(quad * 4 + i) * 68 + s * 16 + r] = bfs(v);
      }
    }
#pragma unroll
    for (int j = 0; j < 2; j++) {
      int chunk = j * 64 + lane;
      int rowr = chunk >> 3, c8 = chunk & 7;
      short8 o = *(const short8*)&mybw[rowr * 68 + c8 * 8];
      *(short8*)((short*)out + (obase + mt * 16 + rowr) * (size_t)nout + nc * 64 + c8 * 8) = o;
    }
  }
}

// ---------------------------------------------------------------- fused FFN chain
// R8 rolling register-prefetch (aligned stride 136); R10: fp32-x residual for
// layer 0 (k_transpose deleted).
__global__ __launch_bounds__(256) void k_ffn(const bf16* __restrict__ QKV,
                                             const float* __restrict__ xf32,
                                             const float* __restrict__ Wo,
                                             const float* __restrict__ bo,
                                             bf16* __restrict__ X,
                                             const float* __restrict__ g1,
                                             const float* __restrict__ be1,
                                             const float* __restrict__ fW1,
                                             const float* __restrict__ fb1,
                                             const float* __restrict__ fW2,
                                             const float* __restrict__ fb2,
                                             const float* __restrict__ g2,
                                             const float* __restrict__ be2,
                                             size_t wso, int wns, size_t bso, int bns,
                                             int gstride,
                                             const float* __restrict__ W4,
                                             const float* __restrict__ C4,
                                             float* __restrict__ AS,
                                             float* __restrict__ ADv,
                                             float* __restrict__ HW0,
                                             float* __restrict__ HW1,
                                             int dofinal) {
  __shared__ short WS[64 * 136];  // weight chunk
  __shared__ short HB[64 * 136];  // h (bf16); per-wave slice doubles as fp32 bounce
  __shared__ short FB[64 * 136];  // f (bf16); per-wave slice doubles as fp32 bounce
  int node, bt;
  swz_node(blockIdx.x, 4, node, bt);
  int tid = threadIdx.x;
  int w = tid >> 6, lane = tid & 63, r = lane & 15, quad = lane >> 4;
  int rrow = lane >> 2, cg = lane & 3;
  int row0 = bt * 64 + w * 16;  // this wave's first row within the node

  // prefetch attn-out A-frags + residual rows (overlap first staging)
  const short* qrow = (const short*)QKV + ((size_t)node * BB + row0 + r) * 384 + quad * 8;
  short8 af[4];
#pragma unroll
  for (int k0 = 0; k0 < 4; k0++) af[k0] = *(const short8*)(qrow + k0 * 32);
  size_t xoff = ((size_t)node * BB + row0 + rrow) * DD + cg * 32;
  short8 xres[4];
  if (xf32) {
    const float* xr32 = xf32 + ((size_t)(row0 + rrow) * NN + node) * DD + cg * 32;
#pragma unroll
    for (int c = 0; c < 4; c++) {
      float4 a = *(const float4*)(xr32 + c * 8);
      float4 b = *(const float4*)(xr32 + c * 8 + 4);
      short8 v = {bfs(a.x), bfs(a.y), bfs(a.z), bfs(a.w),
                  bfs(b.x), bfs(b.y), bfs(b.z), bfs(b.w)};
      xres[c] = v;
    }
  } else {
#pragma unroll
    for (int c = 0; c < 4; c++)
      xres[c] = *(const short8*)((const short*)X + xoff + c * 8);
  }

  const float* WoN = Wo + wso + (size_t)node * (size_t)wns;
  const float* W1N = fW1 + wso + (size_t)node * (size_t)wns;
  const float* W2N = fW2 + wso + (size_t)node * (size_t)wns;

  floatx4 z = {0.f, 0.f, 0.f, 0.f};
  floatx4 acc[8];
  float vv[32];
  float bv[8];
  float4 wreg[8];

  // ================= phase A: Wo GEMM + residual + LN1 -> h (HB)
  ldw_regs(WoN, tid, wreg);
  st_ws(wreg, WS, tid);
  __syncthreads();
  ldw_regs(WoN + 64 * DD, tid, wreg);  // A1 in flight under gemm A0
#pragma unroll
  for (int s = 0; s < 8; s++) acc[s] = z;
  gemm_q(af, WS, r, quad, &acc[0]);
  __syncthreads();  // WS(A0) reads done
  st_ws(wreg, WS, tid);
  __syncthreads();
  ldw_regs(W1N, tid, wreg);  // B0 in flight under gemm A1 + LN1
  gemm_q(af, WS, r, quad, &acc[4]);

  const float* bpo = bo + bso + (size_t)node * (size_t)bns;
#pragma unroll
  for (int cch = 0; cch < 2; cch++)
#pragma unroll
    for (int s = 0; s < 4; s++) bv[cch * 4 + s] = bpo[cch * 64 + s * 16 + r];

  {
    float* BNC = (float*)&HB[w * 16 * 136];  // [16][68] per-wave fp32 bounce
#pragma unroll
    for (int s = 0; s < 4; s++)
#pragma unroll
      for (int i = 0; i < 4; i++)
        BNC[(quad * 4 + i) * 68 + s * 16 + r] = acc[s][i] + bv[s];
    if (cg < 2) {
#pragma unroll
      for (int j = 0; j < 8; j++) {
        float4 t4 = *(const float4*)&BNC[rrow * 68 + (cg & 1) * 32 + j * 4];
        vv[j * 4 + 0] = t4.x; vv[j * 4 + 1] = t4.y;
        vv[j * 4 + 2] = t4.z; vv[j * 4 + 3] = t4.w;
      }
    }
#pragma unroll
    for (int s = 0; s < 4; s++)
#pragma unroll
      for (int i = 0; i < 4; i++)
        BNC[(quad * 4 + i) * 68 + s * 16 + r] = acc[4 + s][i] + bv[4 + s];
    if (cg >= 2) {
#pragma unroll
      for (int j = 0; j < 8; j++) {
        float4 t4 = *(const float4*)&BNC[rrow * 68 + (cg & 1) * 32 + j * 4];
        vv[j * 4 + 0] = t4.x; vv[j * 4 + 1] = t4.y;
        vv[j * 4 + 2] = t4.z; vv[j * 4 + 3] = t4.w;
      }
    }
  }

  float sum = 0.f;
#pragma unroll
  for (int c = 0; c < 4; c++)
#pragma unroll
    for (int j = 0; j < 8; j++) {
      vv[c * 8 + j] += b2f(xres[c][j]);
      sum += vv[c * 8 + j];
    }
  sum += __shfl_xor(sum, 1);
  sum += __shfl_xor(sum, 2);
  float mean = sum * (1.0f / 128.0f);
  float vs = 0.f;
#pragma unroll
  for (int j = 0; j < 32; j++) {
    float d = vv[j] - mean;
    vs += d * d;
  }
  vs += __shfl_xor(vs, 1);
  vs += __shfl_xor(vs, 2);
  float inv = rsqrtf(vs * (1.0f / 128.0f) + 1e-5f);
  {
    const float* gp = g1 + bso + (size_t)node * gstride + cg * 32;
    const float* bep = be1 + bso + (size_t)node * gstride + cg * 32;
#pragma unroll
    for (int c = 0; c < 8; c++) {
      float4 g4 = *(const float4*)(gp + c * 4);
      float4 b4 = *(const float4*)(bep + c * 4);
      vv[c * 4 + 0] = (vv[c * 4 + 0] - mean) * inv * g4.x + b4.x;
      vv[c * 4 + 1] = (vv[c * 4 + 1] - mean) * inv * g4.y + b4.y;
      vv[c * 4 + 2] = (vv[c * 4 + 2] - mean) * inv * g4.z + b4.z;
      vv[c * 4 + 3] = (vv[c * 4 + 3] - mean) * inv * g4.w + b4.w;
    }
  }
  // h -> HB bf16 (overwrites this wave's bounce region; in-order per-wave LDS)
  {
    short* hrow = &HB[(w * 16 + rrow) * 136 + cg * 32];
#pragma unroll
    for (int c = 0; c < 4; c++) {
      short8 hs;
#pragma unroll
      for (int j = 0; j < 8; j++) hs[j] = bfs(vv[c * 8 + j]);
      *(short8*)(hrow + c * 8) = hs;
    }
  }

  // ================= phase B: f = relu(h@fW1^T + fb1) -> FB
  __syncthreads();  // WS(A1) reads done everywhere; h visible
  st_ws(wreg, WS, tid);  // B0 (waits for its loads)
  __syncthreads();
  ldw_regs(W1N + 64 * DD, tid, wreg);  // B1 in flight under gemm B0
  short8 hf[4];
#pragma unroll
  for (int k0 = 0; k0 < 4; k0++)
    hf[k0] = *(const short8*)&HB[(w * 16 + r) * 136 + quad * 8 + k0 * 32];
#pragma unroll
  for (int s = 0; s < 8; s++) acc[s] = z;
  gemm_q(hf, WS, r, quad, &acc[0]);
  __syncthreads();  // WS(B0) reads done
  st_ws(wreg, WS, tid);  // B1
  __syncthreads();
  ldw_regs(W2N, tid, wreg);  // C0 in flight under gemm B1
  gemm_q(hf, WS, r, quad, &acc[4]);
  {
    const float* bp1 = fb1 + bso + (size_t)node * (size_t)bns;
#pragma unroll
    for (int cch = 0; cch < 2; cch++)
#pragma unroll
      for (int s = 0; s < 4; s++) {
        float bb = bp1[cch * 64 + s * 16 + r];
#pragma unroll
        for (int i = 0; i < 4; i++) {
          float v2 = acc[cch * 4 + s][i] + bb;
          FB[(w * 16 + quad * 4 + i) * 136 + cch * 64 + s * 16 + r] =
              bfs(v2 > 0.f ? v2 : 0.f);
        }
      }
  }

  // ================= phase C: LN2(h + f@fW2^T + fb2) -> X / projections
  __syncthreads();  // WS(B1) reads done; f visible
  st_ws(wreg, WS, tid);  // C0
  __syncthreads();
  ldw_regs(W2N + 64 * DD, tid, wreg);  // C1 in flight under gemm C0
  short8 ff[4];
#pragma unroll
  for (int k0 = 0; k0 < 4; k0++)
    ff[k0] = *(const short8*)&FB[(w * 16 + r) * 136 + quad * 8 + k0 * 32];
#pragma unroll
  for (int s = 0; s < 8; s++) acc[s] = z;
  gemm_q(ff, WS, r, quad, &acc[0]);
  __syncthreads();  // WS(C0) reads done
  st_ws(wreg, WS, tid);  // C1
  __syncthreads();
  gemm_q(ff, WS, r, quad, &acc[4]);

  const float* bp2 = fb2 + bso + (size_t)node * (size_t)bns;
#pragma unroll
  for (int cch = 0; cch < 2; cch++)
#pragma unroll
    for (int s = 0; s < 4; s++) bv[cch * 4 + s] = bp2[cch * 64 + s * 16 + r];

  {
    float* BNC = (float*)&FB[w * 16 * 136];  // FB dead after ff loads (wave-private)
#pragma unroll
    for (int s = 0; s < 4; s++)
#pragma unroll
      for (int i = 0; i < 4; i++)
        BNC[(quad * 4 + i) * 68 + s * 16 + r] = acc[s][i] + bv[s];
    if (cg < 2) {
#pragma unroll
      for (int j = 0; j < 8; j++) {
        float4 t4 = *(const float4*)&BNC[rrow * 68 + (cg & 1) * 32 + j * 4];
        vv[j * 4 + 0] = t4.x; vv[j * 4 + 1] = t4.y;
        vv[j * 4 + 2] = t4.z; vv[j * 4 + 3] = t4.w;
      }
    }
#pragma unroll
    for (int s = 0; s < 4; s++)
#pragma unroll
      for (int i = 0; i < 4; i++)
        BNC[(quad * 4 + i) * 68 + s * 16 + r] = acc[4 + s][i] + bv[4 + s];
    if (cg >= 2) {
#pragma unroll
      for (int j = 0; j < 8; j++) {
        float4 t4 = *(const float4*)&BNC[rrow * 68 + (cg & 1) * 32 + j * 4];
        vv[j * 4 + 0] = t4.x; vv[j * 4 + 1] = t4.y;
        vv[j * 4 + 2] = t4.z; vv[j * 4 + 3] = t4.w;
      }
    }
  }

  sum = 0.f;
#pragma unroll
  for (int c = 0; c < 4; c++) {
    short8 hs = *(const short8*)&HB[(w * 16 + rrow) * 136 + cg * 32 + c * 8];
#pragma unroll
    for (int j = 0; j < 8; j++) {
      vv[c * 8 + j] += b2f(hs[j]);
      sum += vv[c * 8 + j];
    }
  }
  sum += __shfl_xor(sum, 1);
  sum += __shfl_xor(sum, 2);
  mean = sum * (1.0f / 128.0f);
  vs = 0.f;
#pragma unroll
  for (int j = 0; j < 32; j++) {
    float d = vv[j] - mean;
    vs += d * d;
  }
  vs += __shfl_xor(vs, 1);
  vs += __shfl_xor(vs, 2);
  inv = rsqrtf(vs * (1.0f / 128.0f) + 1e-5f);
  {
    const float* gp = g2 + bso + (size_t)node * gstride + cg * 32;
    const float* bep = be2 + bso + (size_t)node * gstride + cg * 32;
#pragma unroll
    for (int c = 0; c < 8; c++) {
      float4 g4 = *(const float4*)(gp + c * 4);
      float4 b4 = *(const float4*)(bep + c * 4);
      vv[c * 4 + 0] = (vv[c * 4 + 0] - mean) * inv * g4.x + b4.x;
      vv[c * 4 + 1] = (vv[c * 4 + 1] - mean) * inv * g4.y + b4.y;
      vv[c * 4 + 2] = (vv[c * 4 + 2] - mean) * inv * g4.z + b4.z;
      vv[c * 4 + 3] = (vv[c * 4 + 3] - mean) * inv * g4.w + b4.w;
    }
  }

  if (!dofinal) {
#pragma unroll
    for (int c = 0; c < 4; c++) {
      short8 os;
#pragma unroll
      for (int j = 0; j < 8; j++) os[j] = bfs(vv[c * 8 + j]);
      *(short8*)((short*)X + xoff + c * 8) = os;
    }
  } else {
    float a0 = 0.f, a1 = 0.f, a2 = 0.f, a3 = 0.f;
#pragma unroll
    for (int c = 0; c < 8; c++) {
      float4 w0 = *(const float4*)(W4 + cg * 32 + c * 4);
      float4 w1 = *(const float4*)(W4 + 128 + cg * 32 + c * 4);
      float4 w2 = *(const float4*)(W4 + 256 + cg * 32 + c * 4);
      float4 w3 = *(const float4*)(W4 + 384 + cg * 32 + c * 4);
      a0 += vv[c * 4] * w0.x + vv[c * 4 + 1] * w0.y + vv[c * 4 + 2] * w0.z + vv[c * 4 + 3] * w0.w;
      a1 += vv[c * 4] * w1.x + vv[c * 4 + 1] * w1.y + vv[c * 4 + 2] * w1.z + vv[c * 4 + 3] * w1.w;
      a2 += vv[c * 4] * w2.x + vv[c * 4 + 1] * w2.y + vv[c * 4 + 2] * w2.z + vv[c * 4 + 3] * w2.w;
      a3 += vv[c * 4] * w3.x + vv[c * 4 + 1] * w3.y + vv[c * 4 + 2] * w3.z + vv[c * 4 + 3] * w3.w;
    }
    a0 += __shfl_xor(a0, 1); a0 += __shfl_xor(a0, 2);
    a1 += __shfl_xor(a1, 1); a1 += __shfl_xor(a1, 2);
    a2 += __shfl_xor(a2, 1); a2 += __shfl_xor(a2, 2);
    a3 += __shfl_xor(a3, 1); a3 += __shfl_xor(a3, 2);
    if (cg == 0) {
      int grow = node * BB + row0 + rrow;
      AS[grow] = a0 + C4[0];
      ADv[grow] = a1 + C4[1];
      HW0[grow] = a2 + C4[2];
      HW1[grow] = a3 + C4[3];
    }
  }
}

// ---------------------------------------------------------------- MFMA attention
__global__ __launch_bounds__(256) void k_attn(bf16* __restrict__ QKV) {
  __shared__ short VT[32 * 264];
  __shared__ short Pw[4 * 2560];
  int node, h;
  swz_node(blockIdx.x, 4, node, h);
  int tid = threadIdx.x;
  int wave = tid >> 6, lane = tid & 63, quad = lane >> 4, l15 = lane & 15;
  short* sbase = (short*)(QKV + (size_t)node * BB * 384);

  int q0 = wave * 64;
  short8 qf[4];
#pragma unroll
  for (int qt = 0; qt < 4; qt++)
    qf[qt] = *(const short8*)(sbase + (size_t)(q0 + qt * 16 + l15) * 384 + h * 32 + quad * 8);

#pragma unroll
  for (int it = 0; it < 4; it++) {
    int i = it * 256 + tid;
    int key = i >> 2, dq = (i & 3) << 3;
    short8 v8 = *(const short8*)(sbase + (size_t)key * 384 + 256 + h * 32 + dq);
#pragma unroll
    for (int j = 0; j < 8; j++) VT[(dq + j) * 264 + key] = v8[j];
  }
  __syncthreads();

  floatx4 zz = {0.f, 0.f, 0.f, 0.f};
  floatx4 acc[2][4];
#pragma unroll
  for (int dt = 0; dt < 2; dt++)
#pragma unroll
    for (int qt = 0; qt < 4; qt++) acc[dt][qt] = zz;
  float lp[4] = {0.f, 0.f, 0.f, 0.f};
  const float scale = 0.17677669529663689f;
  short* mypw = &Pw[wave * 2560];

#define KADDR(kt) (const short8*)(sbase + (size_t)((kt) * 16 + l15) * 384 + 128 + h * 32 + quad * 8)
  short8 kfA = *KADDR(0);
  short8 kfB = *KADDR(1);

  for (int g = 0; g < 8; g++) {
    short8 vf0 = *(const short8*)(&VT[l15 * 264 + g * 32 + quad * 8]);
    short8 vf1 = *(const short8*)(&VT[(16 + l15) * 264 + g * 32 + quad * 8]);
    short8 nA = kfA, nB = kfB;
    if (g < 7) {
      nA = *KADDR(g * 2 + 2);
      nB = *KADDR(g * 2 + 3);
    }
#pragma unroll
    for (int sub = 0; sub < 2; sub++) {
      short8 kf = sub ? kfB : kfA;
#pragma unroll
      for (int qt = 0; qt < 4; qt++) {
        floatx4 st = __builtin_amdgcn_mfma_f32_16x16x32_bf16(kf, qf[qt], zz, 0, 0, 0);
        float e0 = __expf(st[0] * scale);
        float e1 = __expf(st[1] * scale);
        float e2 = __expf(st[2] * scale);
        float e3 = __expf(st[3] * scale);
        lp[qt] += (e0 + e1) + (e2 + e3);
        short4a p = {bfs(e0), bfs(e1), bfs(e2), bfs(e3)};
        *(short4a*)(mypw + qt * 640 + l15 * 40 + sub * 16 + quad * 4) = p;
      }
    }
#pragma unroll
    for (int qt = 0; qt < 4; qt++) {
      short8 pf = *(const short8*)(mypw + qt * 640 + l15 * 40 + quad * 8);
      acc[0][qt] = __builtin_amdgcn_mfma_f32_16x16x32_bf16(vf0, pf, acc[0][qt], 0, 0, 0);
      acc[1][qt] = __builtin_amdgcn_mfma_f32_16x16x32_bf16(vf1, pf, acc[1][qt], 0, 0, 0);
    }
    kfA = nA;
    kfB = nB;
  }
#undef KADDR

  float inv[4];
#pragma unroll
  for (int qt = 0; qt < 4; qt++) {
    float lq = lp[qt];
    lq += __shfl_xor(lq, 16);
    lq += __shfl_xor(lq, 32);
    inv[qt] = 1.0f / lq;
  }

#pragma unroll
  for (int qt = 0; qt < 4; qt++)
#pragma unroll
    for (int dt = 0; dt < 2; dt++)
#pragma unroll
      for (int i = 0; i < 4; i++)
        mypw[(qt * 16 + l15) * 40 + dt * 16 + quad * 4 + i] = bfs(acc[dt][qt][i] * inv[qt]);

#pragma unroll
  for (int r = 0; r < 4; r++) {
    int chunk = r * 64 + lane;
    int query = chunk >> 2, d8 = (chunk & 3) * 8;
    short8 o = *(const short8*)(mypw + query * 40 + d8);
    *(short8*)(sbase + (size_t)(q0 + query) * 384 + h * 32 + d8) = o;
  }
}

// ---------------------------------------------------------------- fold GAT/pred/fc
__global__ __launch_bounds__(256) void k_prep(const float* __restrict__ gatW,
                                              const float* __restrict__ attS,
                                              const float* __restrict__ attD,
                                              const float* __restrict__ predW,
                                              const float* __restrict__ fcW,
                                              const float* __restrict__ fcb,
                                              float* __restrict__ W4,
                                              float* __restrict__ C4) {
  __shared__ float U[4][64];
  int t = threadIdx.x;
  int tt = t >> 6, f = t & 63;
  float u = 0.f;
  if (tt == 0) {
    for (int g = 0; g < 64; g++) u += gatW[g * 64 + f] * attS[g];
  } else if (tt == 1) {
    for (int g = 0; g < 64; g++) u += gatW[g * 64 + f] * attD[g];
  } else if (tt == 2) {
    for (int g = 0; g < 64; g++) u += gatW[g * 64 + f] * predW[g];
  } else {
    for (int g = 0; g < 64; g++) u += gatW[g * 64 + f] * predW[64 + g];
  }
  U[tt][f] = u;
  __syncthreads();
  for (int idx = t; idx < 512; idx += 256) {
    int v = idx >> 7, d = idx & 127;
    float w = 0.f;
#pragma unroll
    for (int ff = 0; ff < 64; ff++) w += fcW[ff * 128 + d] * U[v][ff];
    W4[v * 128 + d] = w;
  }
  if (t < 4) {
    float c = 0.f;
#pragma unroll
    for (int ff = 0; ff < 64; ff++) c += fcb[ff] * U[t][ff];
    C4[t] = c;
  }
}

// ---------------------------------------------------------------- GAT: one block per batch
__global__ __launch_bounds__(256) void k_gat(const int* __restrict__ EI,
                                             const float* __restrict__ AS,
                                             const float* __restrict__ ADv,
                                             const float* __restrict__ HW0,
                                             const float* __restrict__ HW1,
                                             const float* __restrict__ gatB,
                                             const float* __restrict__ predW,
                                             const float* __restrict__ predB,
                                             float* __restrict__ OUT) {
  __shared__ float sAS[NN], sAD[NN], sH0[NN], sH1[NN];
  __shared__ float n0[NN], n1[NN], den[NN];
  __shared__ float cc[2];
  int b = blockIdx.x;
  int t = threadIdx.x;
  int base = b * NN;
  for (int i = t; i < NN; i += 256) {
    sAS[i] = AS[base + i];
    sAD[i] = ADv[base + i];
    sH0[i] = HW0[base + i];
    sH1[i] = HW1[base + i];
    n0[i] = 0.f;
    n1[i] = 0.f;
    den[i] = 0.f;
  }
  if (t < 64) {
    float p0 = gatB[t] * predW[t];
    float p1 = gatB[t] * predW[64 + t];
#pragma unroll
    for (int off = 32; off; off >>= 1) {
      p0 += __shfl_down(p0, off);
      p1 += __shfl_down(p1, off);
    }
    if (t == 0) {
      cc[0] = p0 + predB[0];
      cc[1] = p1 + predB[1];
    }
  }
  __syncthreads();

  for (int i = t; i < NE + NN; i += 256) {
    int s, d;
    if (i < NE) {
      s = EI[i];
      d = EI[NE + i];
    } else {
      s = d = i - NE;  // self loop
    }
    float ev = sAS[s] + sAD[d];
    float lr = ev > 0.f ? ev : 0.2f * ev;
    float w = __expf(lr);
    atomicAdd(&n0[d], w * sH0[s]);
    atomicAdd(&n1[d], w * sH1[s]);
    atomicAdd(&den[d], w);
  }
  __syncthreads();

  for (int i = t; i < NN; i += 256) {
    float inv = 1.0f / (den[i] + 1e-16f);
    OUT[2 * (base + i)] = n0[i] * inv + cc[0];
    OUT[2 * (base + i) + 1] = n1[i] * inv + cc[1];
  }
}

// ================================================================ launch
extern "C" void kernel_launch(void* const* d_in, const int* in_sizes, int n_in,
                              void* d_out, int out_size, void* d_ws, size_t ws_size,
                              hipStream_t stream) {
  const float* x = (const float*)d_in[0];
  const int* ei = (const int*)d_in[1];
  const float* Wqkv = (const float*)d_in[2];
  const float* bqkv = (const float*)d_in[3];
  const float* Wo = (const float*)d_in[4];
  const float* bo = (const float*)d_in[5];
  const float* g1 = (const float*)d_in[6];
  const float* be1 = (const float*)d_in[7];
  const float* fW1 = (const float*)d_in[8];
  const float* fb1 = (const float*)d_in[9];
  const float* fW2 = (const float*)d_in[10];
  const float* fb2 = (const float*)d_in[11];
  const float* g2 = (const float*)d_in[12];
  const float* be2 = (const float*)d_in[13];
  const float* fcW = (const float*)d_in[14];
  const float* fcb = (const float*)d_in[15];
  const float* gatW = (const float*)d_in[16];
  const float* attS = (const float*)d_in[17];
  const float* attD = (const float*)d_in[18];
  const float* gatB = (const float*)d_in[19];
  const float* predW = (const float*)d_in[20];
  const float* predB = (const float*)d_in[21];

  const size_t NEED = 53477376;
  if (ws_size < NEED) return;

  char* ws = (char*)d_ws;
  bf16* X = (bf16*)(ws);                  // [N][B][128]   0 .. 13,107,200
  bf16* QKV = (bf16*)(ws + 13107200);     // [N][B][384]  .. 52,428,800
  float* W4 = (float*)(ws + 52428800);    // [4][128]
  float* C4 = (float*)(ws + 52430848);    // [4]
  float* AS = (float*)(ws + 52431872);    // [51200]
  float* ADv = (float*)(ws + 52636672);   // [51200]
  float* HW0 = (float*)(ws + 52841472);   // [51200]
  float* HW1 = (float*)(ws + 53046272);   // [51200]

  k_prep<<<1, 256, 0, stream>>>(gatW, attS, attD, predW, fcW, fcb, W4, C4);

  for (int l = 0; l < LL; l++) {
    size_t w3o = (size_t)l * 384 * DD, b3o = (size_t)l * 384;
    size_t wso = (size_t)l * DD * DD, bso = (size_t)l * DD;
    k_gemm64<4><<<6 * NN, 256, 0, stream>>>(X, x, (l == 0) ? 1 : 0, Wqkv, bqkv,
                                            QKV, 384, DD, w3o, LL * 384 * DD,
                                            b3o, LL * 384, 0, 6);
    k_attn<<<NN * 4, 256, 0, stream>>>(QKV);
    k_ffn<<<4 * NN, 256, 0, stream>>>(QKV, (l == 0) ? x : nullptr, Wo, bo, X,
                                      g1, be1, fW1, fb1, fW2, fb2, g2, be2,
                                      wso, LL * DD * DD, bso, LL * DD, LL * DD,
                                      W4, C4, AS, ADv, HW0, HW1,
                                      (l == LL - 1) ? 1 : 0);
  }

  k_gat<<<BB, 256, 0, stream>>>(ei, AS, ADv, HW0, HW1, gatB, predW, predB,
                                (float*)d_out);
}

// Round 11
// 401.604 us; speedup vs baseline: 1.1511x; 1.0233x over previous
//
#include <hip/hip_runtime.h>
#include <hip/hip_bf16.h>

#define NN 200   // nodes
#define BB 256   // batch == attention sequence length
#define DD 128   // d_model == seq
#define DH 32    // head dim
#define NE 1600  // edges
#define LL 2     // layers

typedef short short8 __attribute__((ext_vector_type(8)));
typedef short short4a __attribute__((ext_vector_type(4)));
typedef float floatx4 __attribute__((ext_vector_type(4)));
using bf16 = __hip_bfloat16;

__device__ __forceinline__ short bfs(float x) {
  bf16 h = __float2bfloat16(x);
  return *(short*)&h;
}
__device__ __forceinline__ float b2f(short s) {
  union { unsigned u; float f; } cv;
  cv.u = ((unsigned)(unsigned short)s) << 16;
  return cv.f;
}

// XCD-clustered block decode (R4: FETCH 78->26MB). Requires NN%8==0.
__device__ __forceinline__ void swz_node(int bid, int per_node, int& node, int& rem) {
  int xcd = bid & 7;
  int slot = bid >> 3;
  int q = slot / per_node;
  node = xcd * (NN >> 3) + q;
  rem = slot - q * per_node;
}

// WS row stride = 136 shorts (272B, 16B-aligned rows — R9 erratum: 132 broke
// b128 alignment, +48%). Bank conflicts on bounce paths accepted.

// issue 8 float4 loads of a [64][128] fp32 weight chunk into registers
__device__ __forceinline__ void ldw_regs(const float* __restrict__ wbase, int tid,
                                         float4* vr) {
#pragma unroll
  for (int i = 0; i < 8; i++) vr[i] = *(const float4*)(wbase + (i * 256 + tid) * 4);
}
// convert + write the chunk to WS (bf16, stride 136)
__device__ __forceinline__ void st_ws(const float4* vr, short* WS, int tid) {
#pragma unroll
  for (int i = 0; i < 8; i++) {
    int idx = i * 256 + tid;
    int rw = idx >> 5, k = (idx & 31) << 2;
    short4a p = {bfs(vr[i].x), bfs(vr[i].y), bfs(vr[i].z), bfs(vr[i].w)};
    *(short4a*)&WS[rw * 136 + k] = p;
  }
}
__device__ __forceinline__ void stage_w(const float* __restrict__ wbase,
                                        short* WS, int tid) {
  float4 vr[8];
  ldw_regs(wbase, tid, vr);
  st_ws(vr, WS, tid);
}

// one 16-row x 64-col GEMM quarter against the staged chunk
__device__ __forceinline__ void gemm_q(const short8* af, const short* WS, int r,
                                       int quad, floatx4* acc) {
#pragma unroll
  for (int k0 = 0; k0 < 4; k0++) {
#pragma unroll
    for (int s = 0; s < 4; s++) {
      short8 bq = *(const short8*)&WS[(s * 16 + r) * 136 + quad * 8 + k0 * 32];
      acc[s] = __builtin_amdgcn_mfma_f32_16x16x32_bf16(af[k0], bq, acc[s], 0, 0, 0);
    }
  }
}

// ---------------------------------------------------------------- QKV GEMM
// xdirect: A-operand read straight from fp32 x (transposed indexing) with
// on-the-fly bf16 convert — replaces the old k_transpose kernel for layer 0.
template <int MTPW>
__global__ __launch_bounds__(256) void k_gemm64(const bf16* __restrict__ A,
                                                const float* __restrict__ xsrc,
                                                int xdirect,
                                                const float* __restrict__ W,
                                                const float* __restrict__ bias,
                                                bf16* __restrict__ out, int nout,
                                                int astride, size_t woff, int wns,
                                                size_t boff, int bns, int relu,
                                                int nc_count) {
  __shared__ short WS[64 * 136];  // 17 KB
  const int RSPLIT = 4 / MTPW;
  int per_node = nc_count * RSPLIT;
  int node, rem;
  swz_node(blockIdx.x, per_node, node, rem);
  int nc = rem / RSPLIT;
  int rh = rem - nc * RSPLIT;
  int tid = threadIdx.x;
  int w = tid >> 6, lane = tid & 63, r = lane & 15, quad = lane >> 4;
  int base_row = rh * 128 + w * (MTPW * 16);

  short8 areg[MTPW][4];
  if (xdirect) {
#pragma unroll
    for (int mt = 0; mt < MTPW; mt++) {
      const float* xrow =
          xsrc + ((size_t)(base_row + mt * 16 + r) * NN + node) * DD + quad * 8;
#pragma unroll
      for (int k = 0; k < 4; k++) {
        float4 a = *(const float4*)(xrow + k * 32);
        float4 b = *(const float4*)(xrow + k * 32 + 4);
        short8 v = {bfs(a.x), bfs(a.y), bfs(a.z), bfs(a.w),
                    bfs(b.x), bfs(b.y), bfs(b.z), bfs(b.w)};
        areg[mt][k] = v;
      }
    }
  } else {
#pragma unroll
    for (int mt = 0; mt < MTPW; mt++) {
      const bf16* arow =
          A + ((size_t)node * BB + base_row + mt * 16 + r) * (size_t)astride + quad * 8;
#pragma unroll
      for (int k = 0; k < 4; k++) areg[mt][k] = *(const short8*)(arow + k * 32);
    }
  }

  stage_w(W + woff + (size_t)node * (size_t)wns + (size_t)nc * 64 * DD, WS, tid);
  __syncthreads();

  floatx4 acc[MTPW][4];
  floatx4 z = {0.f, 0.f, 0.f, 0.f};
#pragma unroll
  for (int mt = 0; mt < MTPW; mt++)
#pragma unroll
    for (int s = 0; s < 4; s++) acc[mt][s] = z;

#pragma unroll
  for (int k0 = 0; k0 < 4; k0++) {
    short8 bq[4];
#pragma unroll
    for (int s = 0; s < 4; s++)
      bq[s] = *(const short8*)&WS[(s * 16 + r) * 136 + quad * 8 + k0 * 32];
#pragma unroll
    for (int mt = 0; mt < MTPW; mt++)
#pragma unroll
      for (int s = 0; s < 4; s++)
        acc[mt][s] = __builtin_amdgcn_mfma_f32_16x16x32_bf16(areg[mt][k0], bq[s],
                                                             acc[mt][s], 0, 0, 0);
  }

  const float* bp = bias + boff + (size_t)node * (size_t)bns + nc * 64;
  float bv[4];
#pragma unroll
  for (int s = 0; s < 4; s++) bv[s] = bp[s * 16 + r];

  __syncthreads();  // all waves done reading WS; reuse as store bounce
  short* mybw = &WS[w * 1088];  // per-wave [16][68]
  const size_t obase = (size_t)node * BB + base_row;
#pragma unroll
  for (int mt = 0; mt < MTPW; mt++) {
#pragma unroll
    for (int s = 0; s < 4; s++) {
#pragma unroll
      for (int i = 0; i < 4; i++) {
        float v = acc[mt][s][i] + bv[s];
        if (relu) v = v > 0.f ? v : 0.f;
        mybw[(quad * 4 + i) * 68 + s * 16 + r] = bfs(v);
      }
    }
#pragma unroll
    for (int j = 0; j < 2; j++) {
      int chunk = j * 64 + lane;
      int rowr = chunk >> 3, c8 = chunk & 7;
      short8 o = *(const short8*)&mybw[rowr * 68 + c8 * 8];
      *(short8*)((short*)out + (obase + mt * 16 + rowr) * (size_t)nout + nc * 64 + c8 * 8) = o;
    }
  }
}

// ---------------------------------------------------------------- fused FFN chain
// R11: ping-pong weight buffers WSa/WSb. A chunk's LDS write no longer needs
// a "readers done" barrier (previous chunk's readers used the OTHER buffer,
// fenced >=1 barrier ago): 13 barriers -> 7, and st_ws is no longer
// sandwiched between two barriers. FB (relu output) OVERLAYS WSa during its
// short live window (wave-local rows; ff regs loaded before WSa rewrite,
// BAR5 protects) -> LDS stays 52.2KB, 3 blocks/CU preserved.
__global__ __launch_bounds__(256) void k_ffn(const bf16* __restrict__ QKV,
                                             const float* __restrict__ xf32,
                                             const float* __restrict__ Wo,
                                             const float* __restrict__ bo,
                                             bf16* __restrict__ X,
                                             const float* __restrict__ g1,
                                             const float* __restrict__ be1,
                                             const float* __restrict__ fW1,
                                             const float* __restrict__ fb1,
                                             const float* __restrict__ fW2,
                                             const float* __restrict__ fb2,
                                             const float* __restrict__ g2,
                                             const float* __restrict__ be2,
                                             size_t wso, int wns, size_t bso, int bns,
                                             int gstride,
                                             const float* __restrict__ W4,
                                             const float* __restrict__ C4,
                                             float* __restrict__ AS,
                                             float* __restrict__ ADv,
                                             float* __restrict__ HW0,
                                             float* __restrict__ HW1,
                                             int dofinal) {
  __shared__ short WSa[64 * 136];  // weight ping / FB overlay / C-bounce
  __shared__ short WSb[64 * 136];  // weight pong
  __shared__ short HB[64 * 136];   // h (bf16); per-wave slice doubles as A-bounce
  int node, bt;
  swz_node(blockIdx.x, 4, node, bt);
  int tid = threadIdx.x;
  int w = tid >> 6, lane = tid & 63, r = lane & 15, quad = lane >> 4;
  int rrow = lane >> 2, cg = lane & 3;
  int row0 = bt * 64 + w * 16;  // this wave's first row within the node

  // prefetch attn-out A-frags + residual rows (overlap first staging)
  const short* qrow = (const short*)QKV + ((size_t)node * BB + row0 + r) * 384 + quad * 8;
  short8 af[4];
#pragma unroll
  for (int k0 = 0; k0 < 4; k0++) af[k0] = *(const short8*)(qrow + k0 * 32);
  size_t xoff = ((size_t)node * BB + row0 + rrow) * DD + cg * 32;
  short8 xres[4];
  if (xf32) {
    const float* xr32 = xf32 + ((size_t)(row0 + rrow) * NN + node) * DD + cg * 32;
#pragma unroll
    for (int c = 0; c < 4; c++) {
      float4 a = *(const float4*)(xr32 + c * 8);
      float4 b = *(const float4*)(xr32 + c * 8 + 4);
      short8 v = {bfs(a.x), bfs(a.y), bfs(a.z), bfs(a.w),
                  bfs(b.x), bfs(b.y), bfs(b.z), bfs(b.w)};
      xres[c] = v;
    }
  } else {
#pragma unroll
    for (int c = 0; c < 4; c++)
      xres[c] = *(const short8*)((const short*)X + xoff + c * 8);
  }

  const float* WoN = Wo + wso + (size_t)node * (size_t)wns;
  const float* W1N = fW1 + wso + (size_t)node * (size_t)wns;
  const float* W2N = fW2 + wso + (size_t)node * (size_t)wns;

  floatx4 z = {0.f, 0.f, 0.f, 0.f};
  floatx4 acc[8];
  float vv[32];
  float bv[8];
  float4 wreg[8];

  // ================= phase A: Wo GEMM + residual + LN1 -> h (HB)
  ldw_regs(WoN, tid, wreg);            // c0
  st_ws(wreg, WSa, tid);               // waits c0
  ldw_regs(WoN + 64 * DD, tid, wreg);  // c1 in flight
  __syncthreads();                     // BAR1: WSa(c0) ready
#pragma unroll
  for (int s = 0; s < 8; s++) acc[s] = z;
  gemm_q(af, WSa, r, quad, &acc[0]);   // A0
  st_ws(wreg, WSb, tid);               // c1 (covered by A0; WSb fresh)
  ldw_regs(W1N, tid, wreg);            // c2
  __syncthreads();                     // BAR2: WSb(c1) ready; A0 readers done
  gemm_q(af, WSb, r, quad, &acc[4]);   // A1

  const float* bpo = bo + bso + (size_t)node * (size_t)bns;
#pragma unroll
  for (int cch = 0; cch < 2; cch++)
#pragma unroll
    for (int s = 0; s < 4; s++) bv[cch * 4 + s] = bpo[cch * 64 + s * 16 + r];

  {
    float* BNC = (float*)&HB[w * 16 * 136];  // [16][68] per-wave fp32 bounce
#pragma unroll
    for (int s = 0; s < 4; s++)
#pragma unroll
      for (int i = 0; i < 4; i++)
        BNC[(quad * 4 + i) * 68 + s * 16 + r] = acc[s][i] + bv[s];
    if (cg < 2) {
#pragma unroll
      for (int j = 0; j < 8; j++) {
        float4 t4 = *(const float4*)&BNC[rrow * 68 + (cg & 1) * 32 + j * 4];
        vv[j * 4 + 0] = t4.x; vv[j * 4 + 1] = t4.y;
        vv[j * 4 + 2] = t4.z; vv[j * 4 + 3] = t4.w;
      }
    }
#pragma unroll
    for (int s = 0; s < 4; s++)
#pragma unroll
      for (int i = 0; i < 4; i++)
        BNC[(quad * 4 + i) * 68 + s * 16 + r] = acc[4 + s][i] + bv[4 + s];
    if (cg >= 2) {
#pragma unroll
      for (int j = 0; j < 8; j++) {
        float4 t4 = *(const float4*)&BNC[rrow * 68 + (cg & 1) * 32 + j * 4];
        vv[j * 4 + 0] = t4.x; vv[j * 4 + 1] = t4.y;
        vv[j * 4 + 2] = t4.z; vv[j * 4 + 3] = t4.w;
      }
    }
  }

  float sum = 0.f;
#pragma unroll
  for (int c = 0; c < 4; c++)
#pragma unroll
    for (int j = 0; j < 8; j++) {
      vv[c * 8 + j] += b2f(xres[c][j]);
      sum += vv[c * 8 + j];
    }
  sum += __shfl_xor(sum, 1);
  sum += __shfl_xor(sum, 2);
  float mean = sum * (1.0f / 128.0f);
  float vs = 0.f;
#pragma unroll
  for (int j = 0; j < 32; j++) {
    float d = vv[j] - mean;
    vs += d * d;
  }
  vs += __shfl_xor(vs, 1);
  vs += __shfl_xor(vs, 2);
  float inv = rsqrtf(vs * (1.0f / 128.0f) + 1e-5f);
  {
    const float* gp = g1 + bso + (size_t)node * gstride + cg * 32;
    const float* bep = be1 + bso + (size_t)node * gstride + cg * 32;
#pragma unroll
    for (int c = 0; c < 8; c++) {
      float4 g4 = *(const float4*)(gp + c * 4);
      float4 b4 = *(const float4*)(bep + c * 4);
      vv[c * 4 + 0] = (vv[c * 4 + 0] - mean) * inv * g4.x + b4.x;
      vv[c * 4 + 1] = (vv[c * 4 + 1] - mean) * inv * g4.y + b4.y;
      vv[c * 4 + 2] = (vv[c * 4 + 2] - mean) * inv * g4.z + b4.z;
      vv[c * 4 + 3] = (vv[c * 4 + 3] - mean) * inv * g4.w + b4.w;
    }
  }
  // h -> HB bf16 (overwrites this wave's bounce region; in-order per-wave LDS)
  {
    short* hrow = &HB[(w * 16 + rrow) * 136 + cg * 32];
#pragma unroll
    for (int c = 0; c < 4; c++) {
      short8 hs;
#pragma unroll
      for (int j = 0; j < 8; j++) hs[j] = bfs(vv[c * 8 + j]);
      *(short8*)(hrow + c * 8) = hs;
    }
  }

  // ================= phase B: f = relu(h@fW1^T + fb1) -> WSa overlay
  st_ws(wreg, WSa, tid);               // c2 (WSa readers A0 done >= BAR2)
  ldw_regs(W1N + 64 * DD, tid, wreg);  // c3
  __syncthreads();                     // BAR3: WSa(c2) ready
  short8 hf[4];
#pragma unroll
  for (int k0 = 0; k0 < 4; k0++)       // own wave's h rows (in-order LDS)
    hf[k0] = *(const short8*)&HB[(w * 16 + r) * 136 + quad * 8 + k0 * 32];
#pragma unroll
  for (int s = 0; s < 8; s++) acc[s] = z;
  gemm_q(hf, WSa, r, quad, &acc[0]);   // B0
  st_ws(wreg, WSb, tid);               // c3 (WSb readers A1 done >= BAR3)
  ldw_regs(W2N, tid, wreg);            // c4
  __syncthreads();                     // BAR4: WSb(c3) ready
  gemm_q(hf, WSb, r, quad, &acc[4]);   // B1
  {
    // relu(f) -> WSa overlay (readers B0 done >= BAR4; wave-local rows)
    const float* bp1 = fb1 + bso + (size_t)node * (size_t)bns;
#pragma unroll
    for (int cch = 0; cch < 2; cch++)
#pragma unroll
      for (int s = 0; s < 4; s++) {
        float bb = bp1[cch * 64 + s * 16 + r];
#pragma unroll
        for (int i = 0; i < 4; i++) {
          float v2 = acc[cch * 4 + s][i] + bb;
          WSa[(w * 16 + quad * 4 + i) * 136 + cch * 64 + s * 16 + r] =
              bfs(v2 > 0.f ? v2 : 0.f);
        }
      }
  }
  short8 ff[4];
#pragma unroll
  for (int k0 = 0; k0 < 4; k0++)       // own wave's f rows (in-order LDS)
    ff[k0] = *(const short8*)&WSa[(w * 16 + r) * 136 + quad * 8 + k0 * 32];
  __syncthreads();                     // BAR5: all ff loaded before WSa rewrite

  // ================= phase C: LN2(h + f@fW2^T + fb2) -> X / projections
  st_ws(wreg, WSa, tid);               // c4
  ldw_regs(W2N + 64 * DD, tid, wreg);  // c5
  __syncthreads();                     // BAR6: WSa(c4) ready
#pragma unroll
  for (int s = 0; s < 8; s++) acc[s] = z;
  gemm_q(ff, WSa, r, quad, &acc[0]);   // C0
  st_ws(wreg, WSb, tid);               // c5 (WSb readers B1 done >= BAR5)
  __syncthreads();                     // BAR7: WSb(c5) ready
  gemm_q(ff, WSb, r, quad, &acc[4]);   // C1

  const float* bp2 = fb2 + bso + (size_t)node * (size_t)bns;
#pragma unroll
  for (int cch = 0; cch < 2; cch++)
#pragma unroll
    for (int s = 0; s < 4; s++) bv[cch * 4 + s] = bp2[cch * 64 + s * 16 + r];

  {
    // C-epilogue fp32 bounce via WSa wave slice (C0 readers done >= BAR7;
    // wave-local in-order LDS)
    float* BNC = (float*)&WSa[w * 16 * 136];
#pragma unroll
    for (int s = 0; s < 4; s++)
#pragma unroll
      for (int i = 0; i < 4; i++)
        BNC[(quad * 4 + i) * 68 + s * 16 + r] = acc[s][i] + bv[s];
    if (cg < 2) {
#pragma unroll
      for (int j = 0; j < 8; j++) {
        float4 t4 = *(const float4*)&BNC[rrow * 68 + (cg & 1) * 32 + j * 4];
        vv[j * 4 + 0] = t4.x; vv[j * 4 + 1] = t4.y;
        vv[j * 4 + 2] = t4.z; vv[j * 4 + 3] = t4.w;
      }
    }
#pragma unroll
    for (int s = 0; s < 4; s++)
#pragma unroll
      for (int i = 0; i < 4; i++)
        BNC[(quad * 4 + i) * 68 + s * 16 + r] = acc[4 + s][i] + bv[4 + s];
    if (cg >= 2) {
#pragma unroll
      for (int j = 0; j < 8; j++) {
        float4 t4 = *(const float4*)&BNC[rrow * 68 + (cg & 1) * 32 + j * 4];
        vv[j * 4 + 0] = t4.x; vv[j * 4 + 1] = t4.y;
        vv[j * 4 + 2] = t4.z; vv[j * 4 + 3] = t4.w;
      }
    }
  }

  sum = 0.f;
#pragma unroll
  for (int c = 0; c < 4; c++) {
    short8 hs = *(const short8*)&HB[(w * 16 + rrow) * 136 + cg * 32 + c * 8];
#pragma unroll
    for (int j = 0; j < 8; j++) {
      vv[c * 8 + j] += b2f(hs[j]);
      sum += vv[c * 8 + j];
    }
  }
  sum += __shfl_xor(sum, 1);
  sum += __shfl_xor(sum, 2);
  mean = sum * (1.0f / 128.0f);
  vs = 0.f;
#pragma unroll
  for (int j = 0; j < 32; j++) {
    float d = vv[j] - mean;
    vs += d * d;
  }
  vs += __shfl_xor(vs, 1);
  vs += __shfl_xor(vs, 2);
  inv = rsqrtf(vs * (1.0f / 128.0f) + 1e-5f);
  {
    const float* gp = g2 + bso + (size_t)node * gstride + cg * 32;
    const float* bep = be2 + bso + (size_t)node * gstride + cg * 32;
#pragma unroll
    for (int c = 0; c < 8; c++) {
      float4 g4 = *(const float4*)(gp + c * 4);
      float4 b4 = *(const float4*)(bep + c * 4);
      vv[c * 4 + 0] = (vv[c * 4 + 0] - mean) * inv * g4.x + b4.x;
      vv[c * 4 + 1] = (vv[c * 4 + 1] - mean) * inv * g4.y + b4.y;
      vv[c * 4 + 2] = (vv[c * 4 + 2] - mean) * inv * g4.z + b4.z;
      vv[c * 4 + 3] = (vv[c * 4 + 3] - mean) * inv * g4.w + b4.w;
    }
  }

  if (!dofinal) {
#pragma unroll
    for (int c = 0; c < 4; c++) {
      short8 os;
#pragma unroll
      for (int j = 0; j < 8; j++) os[j] = bfs(vv[c * 8 + j]);
      *(short8*)((short*)X + xoff + c * 8) = os;
    }
  } else {
    float a0 = 0.f, a1 = 0.f, a2 = 0.f, a3 = 0.f;
#pragma unroll
    for (int c = 0; c < 8; c++) {
      float4 w0 = *(const float4*)(W4 + cg * 32 + c * 4);
      float4 w1 = *(const float4*)(W4 + 128 + cg * 32 + c * 4);
      float4 w2 = *(const float4*)(W4 + 256 + cg * 32 + c * 4);
      float4 w3 = *(const float4*)(W4 + 384 + cg * 32 + c * 4);
      a0 += vv[c * 4] * w0.x + vv[c * 4 + 1] * w0.y + vv[c * 4 + 2] * w0.z + vv[c * 4 + 3] * w0.w;
      a1 += vv[c * 4] * w1.x + vv[c * 4 + 1] * w1.y + vv[c * 4 + 2] * w1.z + vv[c * 4 + 3] * w1.w;
      a2 += vv[c * 4] * w2.x + vv[c * 4 + 1] * w2.y + vv[c * 4 + 2] * w2.z + vv[c * 4 + 3] * w2.w;
      a3 += vv[c * 4] * w3.x + vv[c * 4 + 1] * w3.y + vv[c * 4 + 2] * w3.z + vv[c * 4 + 3] * w3.w;
    }
    a0 += __shfl_xor(a0, 1); a0 += __shfl_xor(a0, 2);
    a1 += __shfl_xor(a1, 1); a1 += __shfl_xor(a1, 2);
    a2 += __shfl_xor(a2, 1); a2 += __shfl_xor(a2, 2);
    a3 += __shfl_xor(a3, 1); a3 += __shfl_xor(a3, 2);
    if (cg == 0) {
      int grow = node * BB + row0 + rrow;
      AS[grow] = a0 + C4[0];
      ADv[grow] = a1 + C4[1];
      HW0[grow] = a2 + C4[2];
      HW1[grow] = a3 + C4[3];
    }
  }
}

// ---------------------------------------------------------------- MFMA attention
__global__ __launch_bounds__(256) void k_attn(bf16* __restrict__ QKV) {
  __shared__ short VT[32 * 264];
  __shared__ short Pw[4 * 2560];
  int node, h;
  swz_node(blockIdx.x, 4, node, h);
  int tid = threadIdx.x;
  int wave = tid >> 6, lane = tid & 63, quad = lane >> 4, l15 = lane & 15;
  short* sbase = (short*)(QKV + (size_t)node * BB * 384);

  int q0 = wave * 64;
  short8 qf[4];
#pragma unroll
  for (int qt = 0; qt < 4; qt++)
    qf[qt] = *(const short8*)(sbase + (size_t)(q0 + qt * 16 + l15) * 384 + h * 32 + quad * 8);

#pragma unroll
  for (int it = 0; it < 4; it++) {
    int i = it * 256 + tid;
    int key = i >> 2, dq = (i & 3) << 3;
    short8 v8 = *(const short8*)(sbase + (size_t)key * 384 + 256 + h * 32 + dq);
#pragma unroll
    for (int j = 0; j < 8; j++) VT[(dq + j) * 264 + key] = v8[j];
  }
  __syncthreads();

  floatx4 zz = {0.f, 0.f, 0.f, 0.f};
  floatx4 acc[2][4];
#pragma unroll
  for (int dt = 0; dt < 2; dt++)
#pragma unroll
    for (int qt = 0; qt < 4; qt++) acc[dt][qt] = zz;
  float lp[4] = {0.f, 0.f, 0.f, 0.f};
  const float scale = 0.17677669529663689f;
  short* mypw = &Pw[wave * 2560];

#define KADDR(kt) (const short8*)(sbase + (size_t)((kt) * 16 + l15) * 384 + 128 + h * 32 + quad * 8)
  short8 kfA = *KADDR(0);
  short8 kfB = *KADDR(1);

  for (int g = 0; g < 8; g++) {
    short8 vf0 = *(const short8*)(&VT[l15 * 264 + g * 32 + quad * 8]);
    short8 vf1 = *(const short8*)(&VT[(16 + l15) * 264 + g * 32 + quad * 8]);
    short8 nA = kfA, nB = kfB;
    if (g < 7) {
      nA = *KADDR(g * 2 + 2);
      nB = *KADDR(g * 2 + 3);
    }
#pragma unroll
    for (int sub = 0; sub < 2; sub++) {
      short8 kf = sub ? kfB : kfA;
#pragma unroll
      for (int qt = 0; qt < 4; qt++) {
        floatx4 st = __builtin_amdgcn_mfma_f32_16x16x32_bf16(kf, qf[qt], zz, 0, 0, 0);
        float e0 = __expf(st[0] * scale);
        float e1 = __expf(st[1] * scale);
        float e2 = __expf(st[2] * scale);
        float e3 = __expf(st[3] * scale);
        lp[qt] += (e0 + e1) + (e2 + e3);
        short4a p = {bfs(e0), bfs(e1), bfs(e2), bfs(e3)};
        *(short4a*)(mypw + qt * 640 + l15 * 40 + sub * 16 + quad * 4) = p;
      }
    }
#pragma unroll
    for (int qt = 0; qt < 4; qt++) {
      short8 pf = *(const short8*)(mypw + qt * 640 + l15 * 40 + quad * 8);
      acc[0][qt] = __builtin_amdgcn_mfma_f32_16x16x32_bf16(vf0, pf, acc[0][qt], 0, 0, 0);
      acc[1][qt] = __builtin_amdgcn_mfma_f32_16x16x32_bf16(vf1, pf, acc[1][qt], 0, 0, 0);
    }
    kfA = nA;
    kfB = nB;
  }
#undef KADDR

  float inv[4];
#pragma unroll
  for (int qt = 0; qt < 4; qt++) {
    float lq = lp[qt];
    lq += __shfl_xor(lq, 16);
    lq += __shfl_xor(lq, 32);
    inv[qt] = 1.0f / lq;
  }

#pragma unroll
  for (int qt = 0; qt < 4; qt++)
#pragma unroll
    for (int dt = 0; dt < 2; dt++)
#pragma unroll
      for (int i = 0; i < 4; i++)
        mypw[(qt * 16 + l15) * 40 + dt * 16 + quad * 4 + i] = bfs(acc[dt][qt][i] * inv[qt]);

#pragma unroll
  for (int r = 0; r < 4; r++) {
    int chunk = r * 64 + lane;
    int query = chunk >> 2, d8 = (chunk & 3) * 8;
    short8 o = *(const short8*)(mypw + query * 40 + d8);
    *(short8*)(sbase + (size_t)(q0 + query) * 384 + h * 32 + d8) = o;
  }
}

// ---------------------------------------------------------------- fold GAT/pred/fc
__global__ __launch_bounds__(256) void k_prep(const float* __restrict__ gatW,
                                              const float* __restrict__ attS,
                                              const float* __restrict__ attD,
                                              const float* __restrict__ predW,
                                              const float* __restrict__ fcW,
                                              const float* __restrict__ fcb,
                                              float* __restrict__ W4,
                                              float* __restrict__ C4) {
  __shared__ float U[4][64];
  int t = threadIdx.x;
  int tt = t >> 6, f = t & 63;
  float u = 0.f;
  if (tt == 0) {
    for (int g = 0; g < 64; g++) u += gatW[g * 64 + f] * attS[g];
  } else if (tt == 1) {
    for (int g = 0; g < 64; g++) u += gatW[g * 64 + f] * attD[g];
  } else if (tt == 2) {
    for (int g = 0; g < 64; g++) u += gatW[g * 64 + f] * predW[g];
  } else {
    for (int g = 0; g < 64; g++) u += gatW[g * 64 + f] * predW[64 + g];
  }
  U[tt][f] = u;
  __syncthreads();
  for (int idx = t; idx < 512; idx += 256) {
    int v = idx >> 7, d = idx & 127;
    float w = 0.f;
#pragma unroll
    for (int ff = 0; ff < 64; ff++) w += fcW[ff * 128 + d] * U[v][ff];
    W4[v * 128 + d] = w;
  }
  if (t < 4) {
    float c = 0.f;
#pragma unroll
    for (int ff = 0; ff < 64; ff++) c += fcb[ff] * U[t][ff];
    C4[t] = c;
  }
}

// ---------------------------------------------------------------- GAT: one block per batch
__global__ __launch_bounds__(256) void k_gat(const int* __restrict__ EI,
                                             const float* __restrict__ AS,
                                             const float* __restrict__ ADv,
                                             const float* __restrict__ HW0,
                                             const float* __restrict__ HW1,
                                             const float* __restrict__ gatB,
                                             const float* __restrict__ predW,
                                             const float* __restrict__ predB,
                                             float* __restrict__ OUT) {
  __shared__ float sAS[NN], sAD[NN], sH0[NN], sH1[NN];
  __shared__ float n0[NN], n1[NN], den[NN];
  __shared__ float cc[2];
  int b = blockIdx.x;
  int t = threadIdx.x;
  int base = b * NN;
  for (int i = t; i < NN; i += 256) {
    sAS[i] = AS[base + i];
    sAD[i] = ADv[base + i];
    sH0[i] = HW0[base + i];
    sH1[i] = HW1[base + i];
    n0[i] = 0.f;
    n1[i] = 0.f;
    den[i] = 0.f;
  }
  if (t < 64) {
    float p0 = gatB[t] * predW[t];
    float p1 = gatB[t] * predW[64 + t];
#pragma unroll
    for (int off = 32; off; off >>= 1) {
      p0 += __shfl_down(p0, off);
      p1 += __shfl_down(p1, off);
    }
    if (t == 0) {
      cc[0] = p0 + predB[0];
      cc[1] = p1 + predB[1];
    }
  }
  __syncthreads();

  for (int i = t; i < NE + NN; i += 256) {
    int s, d;
    if (i < NE) {
      s = EI[i];
      d = EI[NE + i];
    } else {
      s = d = i - NE;  // self loop
    }
    float ev = sAS[s] + sAD[d];
    float lr = ev > 0.f ? ev : 0.2f * ev;
    float w = __expf(lr);
    atomicAdd(&n0[d], w * sH0[s]);
    atomicAdd(&n1[d], w * sH1[s]);
    atomicAdd(&den[d], w);
  }
  __syncthreads();

  for (int i = t; i < NN; i += 256) {
    float inv = 1.0f / (den[i] + 1e-16f);
    OUT[2 * (base + i)] = n0[i] * inv + cc[0];
    OUT[2 * (base + i) + 1] = n1[i] * inv + cc[1];
  }
}

// ================================================================ launch
extern "C" void kernel_launch(void* const* d_in, const int* in_sizes, int n_in,
                              void* d_out, int out_size, void* d_ws, size_t ws_size,
                              hipStream_t stream) {
  const float* x = (const float*)d_in[0];
  const int* ei = (const int*)d_in[1];
  const float* Wqkv = (const float*)d_in[2];
  const float* bqkv = (const float*)d_in[3];
  const float* Wo = (const float*)d_in[4];
  const float* bo = (const float*)d_in[5];
  const float* g1 = (const float*)d_in[6];
  const float* be1 = (const float*)d_in[7];
  const float* fW1 = (const float*)d_in[8];
  const float* fb1 = (const float*)d_in[9];
  const float* fW2 = (const float*)d_in[10];
  const float* fb2 = (const float*)d_in[11];
  const float* g2 = (const float*)d_in[12];
  const float* be2 = (const float*)d_in[13];
  const float* fcW = (const float*)d_in[14];
  const float* fcb = (const float*)d_in[15];
  const float* gatW = (const float*)d_in[16];
  const float* attS = (const float*)d_in[17];
  const float* attD = (const float*)d_in[18];
  const float* gatB = (const float*)d_in[19];
  const float* predW = (const float*)d_in[20];
  const float* predB = (const float*)d_in[21];

  const size_t NEED = 53477376;
  if (ws_size < NEED) return;

  char* ws = (char*)d_ws;
  bf16* X = (bf16*)(ws);                  // [N][B][128]   0 .. 13,107,200
  bf16* QKV = (bf16*)(ws + 13107200);     // [N][B][384]  .. 52,428,800
  float* W4 = (float*)(ws + 52428800);    // [4][128]
  float* C4 = (float*)(ws + 52430848);    // [4]
  float* AS = (float*)(ws + 52431872);    // [51200]
  float* ADv = (float*)(ws + 52636672);   // [51200]
  float* HW0 = (float*)(ws + 52841472);   // [51200]
  float* HW1 = (float*)(ws + 53046272);   // [51200]

  k_prep<<<1, 256, 0, stream>>>(gatW, attS, attD, predW, fcW, fcb, W4, C4);

  for (int l = 0; l < LL; l++) {
    size_t w3o = (size_t)l * 384 * DD, b3o = (size_t)l * 384;
    size_t wso = (size_t)l * DD * DD, bso = (size_t)l * DD;
    k_gemm64<4><<<6 * NN, 256, 0, stream>>>(X, x, (l == 0) ? 1 : 0, Wqkv, bqkv,
                                            QKV, 384, DD, w3o, LL * 384 * DD,
                                            b3o, LL * 384, 0, 6);
    k_attn<<<NN * 4, 256, 0, stream>>>(QKV);
    k_ffn<<<4 * NN, 256, 0, stream>>>(QKV, (l == 0) ? x : nullptr, Wo, bo, X,
                                      g1, be1, fW1, fb1, fW2, fb2, g2, be2,
                                      wso, LL * DD * DD, bso, LL * DD, LL * DD,
                                      W4, C4, AS, ADv, HW0, HW1,
                                      (l == LL - 1) ? 1 : 0);
  }

  k_gat<<<BB, 256, 0, stream>>>(ei, AS, ADv, HW0, HW1, gatB, predW, predB,
                                (float*)d_out);
}